// Round 9
// baseline (1093.442 us; speedup 1.0000x reference)
//
#include <hip/hip_runtime.h>

// Problem constants
#define B_    16384
#define F_    8
#define L_    16
#define K_    4
#define SEQS_ (B_ * F_)   // 131072

// log2(e) / sqrt(2): folded into Wq/bq at convert time
#define SCORE_SCALE 1.02040774484936f

typedef _Float16 h2  __attribute__((ext_vector_type(2)));
typedef _Float16 h8v __attribute__((ext_vector_type(8)));

#if __has_builtin(__builtin_amdgcn_fdot2)
__device__ __forceinline__ float fdot2(h2 a, h2 b, float c) {
    return __builtin_amdgcn_fdot2(a, b, c, false);   // v_dot2_f32_f16
}
#else
__device__ __forceinline__ float fdot2(h2 a, h2 b, float c) {
    return c + (float)a[0] * (float)b[0] + (float)a[1] * (float)b[1];
}
#endif

__device__ __forceinline__ unsigned pku(float a, float b) {
    return __builtin_bit_cast(unsigned, __builtin_amdgcn_cvt_pkrtz(a, b));
}
__device__ __forceinline__ h2 u2h(unsigned u) {
    return __builtin_bit_cast(h2, u);
}
__device__ __forceinline__ h2 relu2(h2 a) {
#if __has_builtin(__builtin_elementwise_max)
    h2 z = {(_Float16)0.f, (_Float16)0.f};
    return __builtin_elementwise_max(a, z);          // v_pk_max_f16
#else
    h2 r; r[0] = a[0] > (_Float16)0.f ? a[0] : (_Float16)0.f;
          r[1] = a[1] > (_Float16)0.f ? a[1] : (_Float16)0.f;
    return r;
#endif
}

// ---- ws layout (all weights+biases merged; staged to LDS in seq_kernel) ----
#define WOFF_FW   0
#define WOFF_IPW  16
#define WOFF_OW   304
#define WOFF_L1W  400
#define WOFF_L2W  592
#define NW_U      784
#define BOFF_FB   0
#define BOFF_IPB  8
#define BOFF_OB   80
#define BOFF_L1B  104
#define BOFF_L2B  152
#define BOFF_N1G  176
#define BOFF_N1B  200
#define BOFF_N2G  224
#define BOFF_N2B  248
#define NB_F      272
#define FLOORS_OFF 8192

// ---------------- K0: pack weights fp32 -> h2 pairs, copy biases ----------------
__global__ __launch_bounds__(256) void cvt_weights(
    const float* __restrict__ fw,  const float* __restrict__ ipw,
    const float* __restrict__ ow,  const float* __restrict__ l1w,
    const float* __restrict__ l2w,
    const float* __restrict__ fb,  const float* __restrict__ ipb,
    const float* __restrict__ ob,  const float* __restrict__ l1b,
    const float* __restrict__ l2b,
    const float* __restrict__ n1g, const float* __restrict__ n1b,
    const float* __restrict__ n2g, const float* __restrict__ n2b,
    unsigned* __restrict__ ws)
{
    // weights (pairwise pack; q-rows of ipw get SCORE_SCALE folded in)
    for (int i = threadIdx.x; i < NW_U; i += 256) {
        const float* s; int off; float scale = 1.f;
        if (i < WOFF_IPW)      { s = fw;  off = i; }
        else if (i < WOFF_OW)  { s = ipw; off = i - WOFF_IPW;
                                 if (((off % 96) >> 2) < 8) scale = SCORE_SCALE; }
        else if (i < WOFF_L1W) { s = ow;  off = i - WOFF_OW; }
        else if (i < WOFF_L2W) { s = l1w; off = i - WOFF_L1W; }
        else                   { s = l2w; off = i - WOFF_L2W; }
        ws[i] = pku(s[2*off] * scale, s[2*off + 1] * scale);
    }
    // biases / LN params (fp32 copy; q-rows of ipb scaled)
    float* bias = (float*)(ws + NW_U);
    for (int i = threadIdx.x; i < NB_F; i += 256) {
        float v;
        if (i < BOFF_IPB)      v = fb[i];
        else if (i < BOFF_OB)  { int j = i - BOFF_IPB; v = ipb[j];
                                 if ((j % 24) < 8) v *= SCORE_SCALE; }
        else if (i < BOFF_L1B) v = ob[i - BOFF_OB];
        else if (i < BOFF_L2B) v = l1b[i - BOFF_L1B];
        else if (i < BOFF_N1G) v = l2b[i - BOFF_L2B];
        else if (i < BOFF_N1B) v = n1g[i - BOFF_N1G];
        else if (i < BOFF_N2G) v = n1b[i - BOFF_N1B];
        else if (i < BOFF_N2B) v = n2g[i - BOFF_N2G];
        else                   v = n2b[i - BOFF_N2B];
        bias[i] = v;
    }
}

// ---------------- K1: per-sequence transformer, 2 sequences per group ----------------
// 16 lanes per group, one row each; each group runs TWO sequences (slots a/b =
// seq0, seq0+16) with fully SEPARATE named state (no [slot]-indexed arrays ->
// no scratch). 2x ILP per wave, 2x reuse of every LDS weight read.
__global__ __launch_bounds__(256, 6) void seq_kernel(
    const float* __restrict__ gfeats,
    const unsigned* __restrict__ ws)
{
    // kb: row r, column (g*2 + slot). Row stride 35 uint4 (560 B):
    // writes 2-way aliased (free), reads 4 distinct bank-quads (conflict-free).
    __shared__ uint4 kb[16][35];
    // vt: slot s at dword base s*1088 + g*68; [jp][d] h2-over-j-pairs + 4 pad.
    __shared__ unsigned vt_dw[2 * 16 * 68];
    // staged weights + biases (uniform; broadcast reads, 0 conflicts)
    __shared__ unsigned wlds[NW_U + NB_F];

    for (int i = threadIdx.x; i < NW_U + NB_F; i += 256) wlds[i] = ws[i];
    __syncthreads();

    const unsigned* wq  = wlds;
    const float* bias   = (const float*)(wlds + NW_U);
    h8v* floors_h       = (h8v*)((char*)ws + FLOORS_OFF);

    const int tid = threadIdx.x;
    const int g   = tid >> 4;   // group within block (0..15)
    const int r   = tid & 15;   // row within sequence
    const int seq0 = blockIdx.x * 32 + g;       // slot a; slot b = seq0 + 16

    _Float16* vth  = (_Float16*)vt_dw;
    const int vwrA = g*136 + (r>>1)*16 + (r&1); // halfword write base, slot a
    const int vwrB = vwrA + 2176;               // slot b (+1088 dw)
    const int vrdA = g*68;                      // dword read base, slot a
    const int vrdB = vrdA + 1088;
    const int colA = g*2, colB = g*2 + 1;

    const h2 one2 = u2h(0x3C003C00u);

    // 8-dim mat-vec row: a += xx . w[0:4]
    auto mv8 = [&](const h2 (&xx)[4], const unsigned* w, float a) -> float {
#pragma unroll
        for (int p = 0; p < 4; ++p) a = fdot2(xx[p], u2h(w[p]), a);
        return a;
    };

    // --- emb_floor: x = feat @ fw.T + fb ---
    float xa[8], xb[8];
    auto emb = [&](int seq, float (&x)[8]) {
        const float4 f = *reinterpret_cast<const float4*>(gfeats + ((size_t)seq * L_ + r) * 4);
        const h2 f0 = u2h(pku(f.x, f.y)), f1 = u2h(pku(f.z, f.w));
#pragma unroll
        for (int d = 0; d < 8; ++d)
            x[d] = fdot2(f0, u2h(wq[WOFF_FW + d*2]),
                   fdot2(f1, u2h(wq[WOFF_FW + d*2 + 1]), bias[BOFF_FB + d]));
    };
    emb(seq0, xa);
    emb(seq0 + 16, xb);

#pragma unroll
    for (int li = 0; li < 3; ++li) {
        const unsigned* W  = wq + WOFF_IPW + li * 96;   // 24 rows x 4 h2
        const float*    Bq = bias + BOFF_IPB + li * 24;

        h2 xa2[4], xb2[4];
#pragma unroll
        for (int p = 0; p < 4; ++p) {
            xa2[p] = u2h(pku(xa[2*p], xa[2*p+1]));
            xb2[p] = u2h(pku(xb[2*p], xb[2*p+1]));
        }

        // k -> packed fp16 LDS (both slots; each weight read feeds both)
        {
            float ka[8], kv[8];
#pragma unroll
            for (int o = 0; o < 8; ++o) {
                const unsigned* w = W + (8 + o)*4;
                ka[o] = mv8(xa2, w, Bq[8 + o]);
                kv[o] = mv8(xb2, w, Bq[8 + o]);
            }
            uint4 Kp;
            Kp.x = pku(ka[0], ka[1]); Kp.y = pku(ka[2], ka[3]);
            Kp.z = pku(ka[4], ka[5]); Kp.w = pku(ka[6], ka[7]);
            kb[r][colA] = Kp;
            Kp.x = pku(kv[0], kv[1]); Kp.y = pku(kv[2], kv[3]);
            Kp.z = pku(kv[4], kv[5]); Kp.w = pku(kv[6], kv[7]);
            kb[r][colB] = Kp;
        }
        // v -> fp16 pair-transposed LDS (halfword scatter, both slots)
#pragma unroll
        for (int o = 0; o < 8; ++o) {
            const unsigned* w = W + (16 + o)*4;
            vth[vwrA + 2*o] = (_Float16)mv8(xa2, w, Bq[16 + o]);
            vth[vwrB + 2*o] = (_Float16)mv8(xb2, w, Bq[16 + o]);
        }
        // q last (scale pre-folded into W/B): hides the k/v write->read gap
        h2 qa[4], qb[4];
#pragma unroll
        for (int h = 0; h < 4; ++h) {
            const unsigned* w0 = W + (2*h)*4;
            const unsigned* w1 = W + (2*h+1)*4;
            qa[h] = u2h(pku(mv8(xa2, w0, Bq[2*h]), mv8(xa2, w1, Bq[2*h+1])));
            qb[h] = u2h(pku(mv8(xb2, w0, Bq[2*h]), mv8(xb2, w1, Bq[2*h+1])));
        }
        // No __syncthreads: each (slot, group) LDS region is wave-private; DS
        // ops are in-order per wave.

        // --- attention over j-pairs, slots interleaved for ILP ---
        float oa[8] = {0.f,0.f,0.f,0.f,0.f,0.f,0.f,0.f};
        float ob[8] = {0.f,0.f,0.f,0.f,0.f,0.f,0.f,0.f};
        float sma[4] = {0.f,0.f,0.f,0.f};
        float smb[4] = {0.f,0.f,0.f,0.f};

        auto attn_jp = [&](int jp, const h2 (&q2)[4], int col, int vbase,
                           float (&o_)[8], float (&sm)[4]) {
            const uint4 Ka = kb[2*jp][col];
            const uint4 Kb = kb[2*jp + 1][col];
            const uint4 va = *reinterpret_cast<const uint4*>(&vt_dw[vbase + jp*8]);
            const uint4 vb = *reinterpret_cast<const uint4*>(&vt_dw[vbase + jp*8 + 4]);
            const float pa0 = __builtin_amdgcn_exp2f(fdot2(q2[0], u2h(Ka.x), 0.f));
            const float pa1 = __builtin_amdgcn_exp2f(fdot2(q2[1], u2h(Ka.y), 0.f));
            const float pa2 = __builtin_amdgcn_exp2f(fdot2(q2[2], u2h(Ka.z), 0.f));
            const float pa3 = __builtin_amdgcn_exp2f(fdot2(q2[3], u2h(Ka.w), 0.f));
            const float pb0 = __builtin_amdgcn_exp2f(fdot2(q2[0], u2h(Kb.x), 0.f));
            const float pb1 = __builtin_amdgcn_exp2f(fdot2(q2[1], u2h(Kb.y), 0.f));
            const float pb2 = __builtin_amdgcn_exp2f(fdot2(q2[2], u2h(Kb.z), 0.f));
            const float pb3 = __builtin_amdgcn_exp2f(fdot2(q2[3], u2h(Kb.w), 0.f));
            const h2 pp0 = u2h(pku(pa0, pb0));
            const h2 pp1 = u2h(pku(pa1, pb1));
            const h2 pp2 = u2h(pku(pa2, pb2));
            const h2 pp3 = u2h(pku(pa3, pb3));
            sm[0] = fdot2(pp0, one2, sm[0]);
            sm[1] = fdot2(pp1, one2, sm[1]);
            sm[2] = fdot2(pp2, one2, sm[2]);
            sm[3] = fdot2(pp3, one2, sm[3]);
            o_[0] = fdot2(pp0, u2h(va.x), o_[0]);
            o_[1] = fdot2(pp0, u2h(va.y), o_[1]);
            o_[2] = fdot2(pp1, u2h(va.z), o_[2]);
            o_[3] = fdot2(pp1, u2h(va.w), o_[3]);
            o_[4] = fdot2(pp2, u2h(vb.x), o_[4]);
            o_[5] = fdot2(pp2, u2h(vb.y), o_[5]);
            o_[6] = fdot2(pp3, u2h(vb.z), o_[6]);
            o_[7] = fdot2(pp3, u2h(vb.w), o_[7]);
        };
#pragma unroll
        for (int jp = 0; jp < 8; ++jp) {
            attn_jp(jp, qa, colA, vrdA, oa, sma);
            attn_jp(jp, qb, colB, vrdB, ob, smb);
        }

        // --- out-proj + residual + LN1 + FFN + LN2 (per slot) ---
        const unsigned* OW  = wq + WOFF_OW + li * 32;
        const float*    OB  = bias + BOFF_OB + li * 8;
        const unsigned* W1  = wq + WOFF_L1W + li * 64;
        const float*    B1l = bias + BOFF_L1B + li * 16;
        const unsigned* W2  = wq + WOFF_L2W + li * 64;
        const float*    B2l = bias + BOFF_L2B + li * 8;
        const float* G1 = bias + BOFF_N1G + li * 8;
        const float* C1 = bias + BOFF_N1B + li * 8;
        const float* G2 = bias + BOFF_N2G + li * 8;
        const float* C2 = bias + BOFF_N2B + li * 8;

        auto post = [&](float (&x)[8], float (&o_)[8], float (&sm)[4]) {
            h2 o2[4];
#pragma unroll
            for (int h = 0; h < 4; ++h) {
                const float inv = __builtin_amdgcn_rcpf(sm[h]);
                o2[h] = u2h(pku(o_[2*h] * inv, o_[2*h+1] * inv));
            }
            float y[8];
#pragma unroll
            for (int d = 0; d < 8; ++d)
                y[d] = x[d] + mv8(o2, OW + d*4, OB[d]);
            {
                h2 y2[4];
#pragma unroll
                for (int p = 0; p < 4; ++p) y2[p] = u2h(pku(y[2*p], y[2*p+1]));
                float s1 = 0.f, s2 = 0.f;
#pragma unroll
                for (int p = 0; p < 4; ++p) {
                    s1 = fdot2(y2[p], one2, s1);
                    s2 = fdot2(y2[p], y2[p], s2);
                }
                const float m  = s1 * 0.125f;
                const float v  = fmaf(-m, m, s2 * 0.125f);
                const float rs = __builtin_amdgcn_rsqf(v + 1e-5f);
#pragma unroll
                for (int d = 0; d < 8; ++d) x[d] = G1[d] * (y[d] - m) * rs + C1[d];
            }
            // FFN
            h2 xx[4];
#pragma unroll
            for (int p = 0; p < 4; ++p) xx[p] = u2h(pku(x[2*p], x[2*p+1]));
            float hb[16];
#pragma unroll
            for (int o = 0; o < 16; ++o)
                hb[o] = mv8(xx, W1 + o*4, B1l[o]);
            h2 hp[8];
#pragma unroll
            for (int p = 0; p < 8; ++p) hp[p] = relu2(u2h(pku(hb[2*p], hb[2*p+1])));
            float y8[8];
#pragma unroll
            for (int d = 0; d < 8; ++d) {
                const unsigned* w = W2 + d*8;
                float a = B2l[d];
#pragma unroll
                for (int p = 0; p < 8; ++p) a = fdot2(hp[p], u2h(w[p]), a);
                y8[d] = x[d] + a;
            }
            {
                h2 y2[4];
#pragma unroll
                for (int p = 0; p < 4; ++p) y2[p] = u2h(pku(y8[2*p], y8[2*p+1]));
                float s1 = 0.f, s2 = 0.f;
#pragma unroll
                for (int p = 0; p < 4; ++p) {
                    s1 = fdot2(y2[p], one2, s1);
                    s2 = fdot2(y2[p], y2[p], s2);
                }
                const float m  = s1 * 0.125f;
                const float v  = fmaf(-m, m, s2 * 0.125f);
                const float rs = __builtin_amdgcn_rsqf(v + 1e-5f);
#pragma unroll
                for (int d = 0; d < 8; ++d) x[d] = G2[d] * (y8[d] - m) * rs + C2[d];
            }
        };
        post(xa, oa, sma);
        post(xb, ob, smb);
    }

    // --- floors[seq] = sum over L (butterfly in 16-lane segment), store fp16 ---
    auto finish = [&](float (&x)[8], int seq) {
#pragma unroll
        for (int d = 0; d < 8; ++d) {
            float t = x[d];
            t += __shfl_xor(t, 1, 16);
            t += __shfl_xor(t, 2, 16);
            t += __shfl_xor(t, 4, 16);
            t += __shfl_xor(t, 8, 16);
            x[d] = t;
        }
        if (r == 0) {
            union { h8v v; unsigned u[4]; } O;
            O.u[0] = pku(x[0], x[1]); O.u[1] = pku(x[2], x[3]);
            O.u[2] = pku(x[4], x[5]); O.u[3] = pku(x[6], x[7]);
            floors_h[seq] = O.v;
        }
    };
    finish(xa, seq0);
    finish(xb, seq0 + 16);
}

// ---------------- K2: per-batch tail (units + match MLP) ----------------
__global__ __launch_bounds__(64) void tail_kernel(
    const int*   __restrict__ cidxs, const int* __restrict__ slots,
    const float* __restrict__ f2,    const float* __restrict__ f3,
    const float* __restrict__ tab_c, const float* __restrict__ tab_s,
    const float* __restrict__ uw,    const float* __restrict__ ub,
    const float* __restrict__ w1,    const float* __restrict__ b1,
    const float* __restrict__ w2,    const float* __restrict__ b2,
    const h8v*   __restrict__ floors_h, float* __restrict__ out)
{
    const int b = blockIdx.x * 64 + threadIdx.x;
    if (b >= B_) return;

    float units[16];
#pragma unroll
    for (int o = 0; o < 16; ++o) units[o] = 0.f;
    for (int fl_i = 0; fl_i < F_; ++fl_i) {
        union { h8v v; _Float16 s[8]; } U;
        U.v = floors_h[(size_t)b * F_ + fl_i];
        float fl[8];
#pragma unroll
        for (int d = 0; d < 8; ++d) fl[d] = (float)U.s[d];
#pragma unroll
        for (int o = 0; o < 16; ++o) {
            float t = ub[o];
#pragma unroll
            for (int d = 0; d < 8; ++d) t += fl[d] * uw[o*8 + d];
            units[o] += fmaxf(t, 0.f);
        }
    }

    float z36[36];
    {
        const int ci = cidxs[b], si = slots[b];
#pragma unroll
        for (int j = 0; j < 8; ++j) z36[j]     = tab_c[(size_t)ci * 8 + j];
#pragma unroll
        for (int j = 0; j < 8; ++j) z36[8 + j] = tab_s[(size_t)si * 8 + j];
#pragma unroll
        for (int j = 0; j < 16; ++j) z36[16 + j] = units[j];
#pragma unroll
        for (int j = 0; j < 4; ++j) z36[32 + j] = f2[(size_t)b * 4 + j];
    }

    float base[20];
#pragma unroll
    for (int o = 0; o < 20; ++o) {
        float t = b1[o];
#pragma unroll
        for (int j = 0; j < 36; ++j) t += z36[j] * w1[o*42 + j];
        base[o] = t;
    }

    const float bb2 = b2[0];
#pragma unroll
    for (int k = 0; k < K_; ++k) {
        float f3v[6];
#pragma unroll
        for (int j = 0; j < 6; ++j) f3v[j] = f3[((size_t)b * K_ + k) * 6 + j];
        float acc = bb2;
#pragma unroll
        for (int o = 0; o < 20; ++o) {
            float t = base[o];
#pragma unroll
            for (int j = 0; j < 6; ++j) t += f3v[j] * w1[o*42 + 36 + j];
            acc += fmaxf(t, 0.f) * w2[o];
        }
        out[(size_t)b * K_ + k] = acc;
    }

    out[(size_t)(B_ * K_) + b] = 4.0f;   // nf3 = K (d_out read as float32)
}

extern "C" void kernel_launch(void* const* d_in, const int* in_sizes, int n_in,
                              void* d_out, int out_size, void* d_ws, size_t ws_size,
                              hipStream_t stream)
{
    const int*   cidxs  = (const int*)  d_in[0];
    const int*   slots  = (const int*)  d_in[1];
    const float* gfeats = (const float*)d_in[2];
    const float* f2     = (const float*)d_in[3];
    const float* f3     = (const float*)d_in[4];
    const float* tab_c  = (const float*)d_in[5];
    const float* tab_s  = (const float*)d_in[6];
    const float* fw     = (const float*)d_in[7];
    const float* fb     = (const float*)d_in[8];
    const float* ipw    = (const float*)d_in[9];
    const float* ipb    = (const float*)d_in[10];
    const float* ow     = (const float*)d_in[11];
    const float* ob     = (const float*)d_in[12];
    const float* l1w    = (const float*)d_in[13];
    const float* l1b    = (const float*)d_in[14];
    const float* l2w    = (const float*)d_in[15];
    const float* l2b    = (const float*)d_in[16];
    const float* n1g    = (const float*)d_in[17];
    const float* n1b    = (const float*)d_in[18];
    const float* n2g    = (const float*)d_in[19];
    const float* n2b    = (const float*)d_in[20];
    const float* uw     = (const float*)d_in[21];
    const float* ub     = (const float*)d_in[22];
    const float* w1     = (const float*)d_in[23];
    const float* b1     = (const float*)d_in[24];
    const float* w2     = (const float*)d_in[25];
    const float* b2     = (const float*)d_in[26];

    unsigned* ws       = (unsigned*)d_ws;
    h8v*      floors_h = (h8v*)((char*)d_ws + FLOORS_OFF);

    cvt_weights<<<1, 256, 0, stream>>>(fw, ipw, ow, l1w, l2w,
                                       fb, ipb, ob, l1b, l2b,
                                       n1g, n1b, n2g, n2b, ws);

    seq_kernel<<<SEQS_ / 32, 256, 0, stream>>>(gfeats, ws);

    tail_kernel<<<B_ / 64, 64, 0, stream>>>(
        cidxs, slots, f2, f3, tab_c, tab_s, uw, ub, w1, b1, w2, b2,
        floors_h, (float*)d_out);
}

// Round 10
// 425.194 us; speedup vs baseline: 2.5716x; 2.5716x over previous
//
#include <hip/hip_runtime.h>

// Problem constants
#define B_    16384
#define F_    8
#define L_    16
#define K_    4
#define SEQS_ (B_ * F_)   // 131072

// log2(e) / sqrt(2): folded into Wq/bq at convert time
#define SCORE_SCALE 1.02040774484936f

typedef _Float16 h2  __attribute__((ext_vector_type(2)));
typedef _Float16 h8v __attribute__((ext_vector_type(8)));

#if __has_builtin(__builtin_amdgcn_fdot2)
__device__ __forceinline__ float fdot2(h2 a, h2 b, float c) {
    return __builtin_amdgcn_fdot2(a, b, c, false);   // v_dot2_f32_f16
}
#else
__device__ __forceinline__ float fdot2(h2 a, h2 b, float c) {
    return c + (float)a[0] * (float)b[0] + (float)a[1] * (float)b[1];
}
#endif

__device__ __forceinline__ unsigned pku(float a, float b) {
    return __builtin_bit_cast(unsigned, __builtin_amdgcn_cvt_pkrtz(a, b));
}
__device__ __forceinline__ h2 u2h(unsigned u) {
    return __builtin_bit_cast(h2, u);
}
__device__ __forceinline__ h2 relu2(h2 a) {
#if __has_builtin(__builtin_elementwise_max)
    h2 z = {(_Float16)0.f, (_Float16)0.f};
    return __builtin_elementwise_max(a, z);          // v_pk_max_f16
#else
    h2 r; r[0] = a[0] > (_Float16)0.f ? a[0] : (_Float16)0.f;
          r[1] = a[1] > (_Float16)0.f ? a[1] : (_Float16)0.f;
    return r;
#endif
}

// ---- ws layout (all weights+biases merged; staged to LDS in seq_kernel) ----
#define WOFF_FW   0
#define WOFF_IPW  16
#define WOFF_OW   304
#define WOFF_L1W  400
#define WOFF_L2W  592
#define NW_U      784
#define BOFF_FB   0
#define BOFF_IPB  8
#define BOFF_OB   80
#define BOFF_L1B  104
#define BOFF_L2B  152
#define BOFF_N1G  176
#define BOFF_N1B  200
#define BOFF_N2G  224
#define BOFF_N2B  248
#define NB_F      272
#define FLOORS_OFF 8192

// ---------------- K0: pack weights fp32 -> h2 pairs, copy biases ----------------
__global__ __launch_bounds__(256) void cvt_weights(
    const float* __restrict__ fw,  const float* __restrict__ ipw,
    const float* __restrict__ ow,  const float* __restrict__ l1w,
    const float* __restrict__ l2w,
    const float* __restrict__ fb,  const float* __restrict__ ipb,
    const float* __restrict__ ob,  const float* __restrict__ l1b,
    const float* __restrict__ l2b,
    const float* __restrict__ n1g, const float* __restrict__ n1b,
    const float* __restrict__ n2g, const float* __restrict__ n2b,
    unsigned* __restrict__ ws)
{
    // weights (pairwise pack; q-rows of ipw get SCORE_SCALE folded in)
    for (int i = threadIdx.x; i < NW_U; i += 256) {
        const float* s; int off; float scale = 1.f;
        if (i < WOFF_IPW)      { s = fw;  off = i; }
        else if (i < WOFF_OW)  { s = ipw; off = i - WOFF_IPW;
                                 if (((off % 96) >> 2) < 8) scale = SCORE_SCALE; }
        else if (i < WOFF_L1W) { s = ow;  off = i - WOFF_OW; }
        else if (i < WOFF_L2W) { s = l1w; off = i - WOFF_L1W; }
        else                   { s = l2w; off = i - WOFF_L2W; }
        ws[i] = pku(s[2*off] * scale, s[2*off + 1] * scale);
    }
    // biases / LN params (fp32 copy; q-rows of ipb scaled)
    float* bias = (float*)(ws + NW_U);
    for (int i = threadIdx.x; i < NB_F; i += 256) {
        float v;
        if (i < BOFF_IPB)      v = fb[i];
        else if (i < BOFF_OB)  { int j = i - BOFF_IPB; v = ipb[j];
                                 if ((j % 24) < 8) v *= SCORE_SCALE; }
        else if (i < BOFF_L1B) v = ob[i - BOFF_OB];
        else if (i < BOFF_L2B) v = l1b[i - BOFF_L1B];
        else if (i < BOFF_N1G) v = l2b[i - BOFF_L2B];
        else if (i < BOFF_N1B) v = n1g[i - BOFF_N1G];
        else if (i < BOFF_N2G) v = n1b[i - BOFF_N1B];
        else if (i < BOFF_N2B) v = n2g[i - BOFF_N2G];
        else                   v = n2b[i - BOFF_N2B];
        bias[i] = v;
    }
}

// ---------------- K1: per-sequence transformer, 2 sequences per group ----------------
// 16 lanes per group; each group runs TWO sequences (a = seq0, b = seq0+16).
// Straight-line duplicated code (no lambdas, no [slot] arrays) so SROA promotes
// everything, as proven in R6/R8. Each weight ds_read feeds both sequences.
__global__ __launch_bounds__(256, 6) void seq_kernel(
    const float* __restrict__ gfeats,
    const unsigned* __restrict__ ws)
{
    // kb: row r, col = g*2 + slot (32 cols). Stride 33 uint4 = 528 B/row:
    // writes 2-way bank aliased (free), reads 4-address broadcast (free).
    __shared__ uint4 kb[16][33];
    // vt: slot base s*1088 dw + g*68; [jp][d] h2-over-j-pairs + 4 pad.
    __shared__ unsigned vt_dw[2 * 16 * 68];
    // staged weights + biases (uniform; broadcast reads, 0 conflicts)
    __shared__ unsigned wlds[NW_U + NB_F];

    for (int i = threadIdx.x; i < NW_U + NB_F; i += 256) wlds[i] = ws[i];
    __syncthreads();

    const unsigned* wq  = wlds;
    const float* bias   = (const float*)(wlds + NW_U);
    h8v* floors_h       = (h8v*)((char*)ws + FLOORS_OFF);

    const int tid = threadIdx.x;
    const int g   = tid >> 4;   // group within block (0..15)
    const int r   = tid & 15;   // row within sequence
    const int seq0 = blockIdx.x * 32 + g;      // slot a; slot b = seq0 + 16

    _Float16* vth  = (_Float16*)vt_dw;
    const int vwrA = g*136 + (r>>1)*16 + (r&1); // halfword write base, slot a
    const int vwrB = vwrA + 2176;               // slot b (+1088 dwords)
    const int vrdA = g*68;                      // dword read base, slot a
    const int vrdB = vrdA + 1088;
    const int colA = g*2, colB = g*2 + 1;

    const h2 one2 = u2h(0x3C003C00u);

    // --- emb_floor: x = feat @ fw.T + fb (both slots) ---
    float xa[8], xb[8];
    {
        const float4 f = *reinterpret_cast<const float4*>(gfeats + ((size_t)seq0 * L_ + r) * 4);
        const h2 f0 = u2h(pku(f.x, f.y)), f1 = u2h(pku(f.z, f.w));
#pragma unroll
        for (int d = 0; d < 8; ++d)
            xa[d] = fdot2(f0, u2h(wq[WOFF_FW + d*2]),
                    fdot2(f1, u2h(wq[WOFF_FW + d*2 + 1]), bias[BOFF_FB + d]));
    }
    {
        const float4 f = *reinterpret_cast<const float4*>(gfeats + ((size_t)(seq0 + 16) * L_ + r) * 4);
        const h2 f0 = u2h(pku(f.x, f.y)), f1 = u2h(pku(f.z, f.w));
#pragma unroll
        for (int d = 0; d < 8; ++d)
            xb[d] = fdot2(f0, u2h(wq[WOFF_FW + d*2]),
                    fdot2(f1, u2h(wq[WOFF_FW + d*2 + 1]), bias[BOFF_FB + d]));
    }

#pragma unroll
    for (int li = 0; li < 3; ++li) {
        const unsigned* W  = wq + WOFF_IPW + li * 96;   // 24 rows x 4 h2
        const float*    Bq = bias + BOFF_IPB + li * 24;

        h2 xa2[4], xb2[4];
#pragma unroll
        for (int p = 0; p < 4; ++p) {
            xa2[p] = u2h(pku(xa[2*p], xa[2*p+1]));
            xb2[p] = u2h(pku(xb[2*p], xb[2*p+1]));
        }

        // k -> packed fp16 LDS (each weight read shared by both slots)
        {
            float ka[8], kc[8];
#pragma unroll
            for (int o = 0; o < 8; ++o) {
                const unsigned* w = W + (8 + o)*4;
                const float bq = Bq[8 + o];
                float aa = bq, ab = bq;
#pragma unroll
                for (int p = 0; p < 4; ++p) {
                    const h2 wp = u2h(w[p]);
                    aa = fdot2(xa2[p], wp, aa);
                    ab = fdot2(xb2[p], wp, ab);
                }
                ka[o] = aa; kc[o] = ab;
            }
            uint4 Kp;
            Kp.x = pku(ka[0], ka[1]); Kp.y = pku(ka[2], ka[3]);
            Kp.z = pku(ka[4], ka[5]); Kp.w = pku(ka[6], ka[7]);
            kb[r][colA] = Kp;
            Kp.x = pku(kc[0], kc[1]); Kp.y = pku(kc[2], kc[3]);
            Kp.z = pku(kc[4], kc[5]); Kp.w = pku(kc[6], kc[7]);
            kb[r][colB] = Kp;
        }
        // v -> fp16 pair-transposed LDS (halfword scatter, both slots)
        {
#pragma unroll
            for (int o = 0; o < 8; ++o) {
                const unsigned* w = W + (16 + o)*4;
                const float bq = Bq[16 + o];
                float aa = bq, ab = bq;
#pragma unroll
                for (int p = 0; p < 4; ++p) {
                    const h2 wp = u2h(w[p]);
                    aa = fdot2(xa2[p], wp, aa);
                    ab = fdot2(xb2[p], wp, ab);
                }
                vth[vwrA + 2*o] = (_Float16)aa;
                vth[vwrB + 2*o] = (_Float16)ab;
            }
        }
        // q last (scale pre-folded into W/B): hides the k/v write->read gap
        h2 qa[4], qb[4];
#pragma unroll
        for (int h = 0; h < 4; ++h) {
            const unsigned* w0 = W + (2*h)*4;
            const unsigned* w1 = W + (2*h+1)*4;
            float a0 = Bq[2*h], a1 = Bq[2*h+1];
            float b0 = a0, b1 = a1;
#pragma unroll
            for (int p = 0; p < 4; ++p) {
                const h2 wp0 = u2h(w0[p]);
                const h2 wp1 = u2h(w1[p]);
                a0 = fdot2(xa2[p], wp0, a0);
                a1 = fdot2(xa2[p], wp1, a1);
                b0 = fdot2(xb2[p], wp0, b0);
                b1 = fdot2(xb2[p], wp1, b1);
            }
            qa[h] = u2h(pku(a0, a1));
            qb[h] = u2h(pku(b0, b1));
        }
        // No __syncthreads: each (slot, group) LDS region is wave-private; DS
        // ops are in-order per wave.

        // --- attention slot a ---
        float oa[8] = {0.f,0.f,0.f,0.f,0.f,0.f,0.f,0.f};
        float sma[4] = {0.f,0.f,0.f,0.f};
#pragma unroll
        for (int jp = 0; jp < 8; ++jp) {
            const uint4 Ka = kb[2*jp][colA];
            const uint4 Kb = kb[2*jp + 1][colA];
            const uint4 va = *reinterpret_cast<const uint4*>(&vt_dw[vrdA + jp*8]);
            const uint4 vb = *reinterpret_cast<const uint4*>(&vt_dw[vrdA + jp*8 + 4]);
            const float pa0 = __builtin_amdgcn_exp2f(fdot2(qa[0], u2h(Ka.x), 0.f));
            const float pa1 = __builtin_amdgcn_exp2f(fdot2(qa[1], u2h(Ka.y), 0.f));
            const float pa2 = __builtin_amdgcn_exp2f(fdot2(qa[2], u2h(Ka.z), 0.f));
            const float pa3 = __builtin_amdgcn_exp2f(fdot2(qa[3], u2h(Ka.w), 0.f));
            const float pb0 = __builtin_amdgcn_exp2f(fdot2(qa[0], u2h(Kb.x), 0.f));
            const float pb1 = __builtin_amdgcn_exp2f(fdot2(qa[1], u2h(Kb.y), 0.f));
            const float pb2 = __builtin_amdgcn_exp2f(fdot2(qa[2], u2h(Kb.z), 0.f));
            const float pb3 = __builtin_amdgcn_exp2f(fdot2(qa[3], u2h(Kb.w), 0.f));
            const h2 pp0 = u2h(pku(pa0, pb0));
            const h2 pp1 = u2h(pku(pa1, pb1));
            const h2 pp2 = u2h(pku(pa2, pb2));
            const h2 pp3 = u2h(pku(pa3, pb3));
            sma[0] = fdot2(pp0, one2, sma[0]);
            sma[1] = fdot2(pp1, one2, sma[1]);
            sma[2] = fdot2(pp2, one2, sma[2]);
            sma[3] = fdot2(pp3, one2, sma[3]);
            oa[0] = fdot2(pp0, u2h(va.x), oa[0]);
            oa[1] = fdot2(pp0, u2h(va.y), oa[1]);
            oa[2] = fdot2(pp1, u2h(va.z), oa[2]);
            oa[3] = fdot2(pp1, u2h(va.w), oa[3]);
            oa[4] = fdot2(pp2, u2h(vb.x), oa[4]);
            oa[5] = fdot2(pp2, u2h(vb.y), oa[5]);
            oa[6] = fdot2(pp3, u2h(vb.z), oa[6]);
            oa[7] = fdot2(pp3, u2h(vb.w), oa[7]);
        }
        // --- attention slot b ---
        float ob[8] = {0.f,0.f,0.f,0.f,0.f,0.f,0.f,0.f};
        float smb[4] = {0.f,0.f,0.f,0.f};
#pragma unroll
        for (int jp = 0; jp < 8; ++jp) {
            const uint4 Ka = kb[2*jp][colB];
            const uint4 Kb = kb[2*jp + 1][colB];
            const uint4 va = *reinterpret_cast<const uint4*>(&vt_dw[vrdB + jp*8]);
            const uint4 vb = *reinterpret_cast<const uint4*>(&vt_dw[vrdB + jp*8 + 4]);
            const float pa0 = __builtin_amdgcn_exp2f(fdot2(qb[0], u2h(Ka.x), 0.f));
            const float pa1 = __builtin_amdgcn_exp2f(fdot2(qb[1], u2h(Ka.y), 0.f));
            const float pa2 = __builtin_amdgcn_exp2f(fdot2(qb[2], u2h(Ka.z), 0.f));
            const float pa3 = __builtin_amdgcn_exp2f(fdot2(qb[3], u2h(Ka.w), 0.f));
            const float pb0 = __builtin_amdgcn_exp2f(fdot2(qb[0], u2h(Kb.x), 0.f));
            const float pb1 = __builtin_amdgcn_exp2f(fdot2(qb[1], u2h(Kb.y), 0.f));
            const float pb2 = __builtin_amdgcn_exp2f(fdot2(qb[2], u2h(Kb.z), 0.f));
            const float pb3 = __builtin_amdgcn_exp2f(fdot2(qb[3], u2h(Kb.w), 0.f));
            const h2 pp0 = u2h(pku(pa0, pb0));
            const h2 pp1 = u2h(pku(pa1, pb1));
            const h2 pp2 = u2h(pku(pa2, pb2));
            const h2 pp3 = u2h(pku(pa3, pb3));
            smb[0] = fdot2(pp0, one2, smb[0]);
            smb[1] = fdot2(pp1, one2, smb[1]);
            smb[2] = fdot2(pp2, one2, smb[2]);
            smb[3] = fdot2(pp3, one2, smb[3]);
            ob[0] = fdot2(pp0, u2h(va.x), ob[0]);
            ob[1] = fdot2(pp0, u2h(va.y), ob[1]);
            ob[2] = fdot2(pp1, u2h(va.z), ob[2]);
            ob[3] = fdot2(pp1, u2h(va.w), ob[3]);
            ob[4] = fdot2(pp2, u2h(vb.x), ob[4]);
            ob[5] = fdot2(pp2, u2h(vb.y), ob[5]);
            ob[6] = fdot2(pp3, u2h(vb.z), ob[6]);
            ob[7] = fdot2(pp3, u2h(vb.w), ob[7]);
        }

        const unsigned* OW  = wq + WOFF_OW + li * 32;
        const float*    OB  = bias + BOFF_OB + li * 8;
        const unsigned* W1  = wq + WOFF_L1W + li * 64;
        const float*    B1l = bias + BOFF_L1B + li * 16;
        const unsigned* W2  = wq + WOFF_L2W + li * 64;
        const float*    B2l = bias + BOFF_L2B + li * 8;
        const float* G1 = bias + BOFF_N1G + li * 8;
        const float* C1 = bias + BOFF_N1B + li * 8;
        const float* G2 = bias + BOFF_N2G + li * 8;
        const float* C2 = bias + BOFF_N2B + li * 8;

        // --- post slot a: out-proj + residual + LN1 + FFN + LN2 ---
        {
            h2 o2[4];
#pragma unroll
            for (int h = 0; h < 4; ++h) {
                const float inv = __builtin_amdgcn_rcpf(sma[h]);
                o2[h] = u2h(pku(oa[2*h] * inv, oa[2*h+1] * inv));
            }
            float y[8];
#pragma unroll
            for (int d = 0; d < 8; ++d) {
                const unsigned* w = OW + d*4;
                float a = OB[d];
#pragma unroll
                for (int p = 0; p < 4; ++p) a = fdot2(o2[p], u2h(w[p]), a);
                y[d] = xa[d] + a;
            }
            {
                h2 y2[4];
#pragma unroll
                for (int p = 0; p < 4; ++p) y2[p] = u2h(pku(y[2*p], y[2*p+1]));
                float s1 = 0.f, s2 = 0.f;
#pragma unroll
                for (int p = 0; p < 4; ++p) {
                    s1 = fdot2(y2[p], one2, s1);
                    s2 = fdot2(y2[p], y2[p], s2);
                }
                const float m  = s1 * 0.125f;
                const float v  = fmaf(-m, m, s2 * 0.125f);
                const float rs = __builtin_amdgcn_rsqf(v + 1e-5f);
#pragma unroll
                for (int d = 0; d < 8; ++d) xa[d] = G1[d] * (y[d] - m) * rs + C1[d];
            }
            h2 xx[4];
#pragma unroll
            for (int p = 0; p < 4; ++p) xx[p] = u2h(pku(xa[2*p], xa[2*p+1]));
            float hb[16];
#pragma unroll
            for (int o = 0; o < 16; ++o) {
                const unsigned* w = W1 + o*4;
                float a = B1l[o];
#pragma unroll
                for (int p = 0; p < 4; ++p) a = fdot2(xx[p], u2h(w[p]), a);
                hb[o] = a;
            }
            h2 hp[8];
#pragma unroll
            for (int p = 0; p < 8; ++p) hp[p] = relu2(u2h(pku(hb[2*p], hb[2*p+1])));
            float y8[8];
#pragma unroll
            for (int d = 0; d < 8; ++d) {
                const unsigned* w = W2 + d*8;
                float a = B2l[d];
#pragma unroll
                for (int p = 0; p < 8; ++p) a = fdot2(hp[p], u2h(w[p]), a);
                y8[d] = xa[d] + a;
            }
            {
                h2 y2[4];
#pragma unroll
                for (int p = 0; p < 4; ++p) y2[p] = u2h(pku(y8[2*p], y8[2*p+1]));
                float s1 = 0.f, s2 = 0.f;
#pragma unroll
                for (int p = 0; p < 4; ++p) {
                    s1 = fdot2(y2[p], one2, s1);
                    s2 = fdot2(y2[p], y2[p], s2);
                }
                const float m  = s1 * 0.125f;
                const float v  = fmaf(-m, m, s2 * 0.125f);
                const float rs = __builtin_amdgcn_rsqf(v + 1e-5f);
#pragma unroll
                for (int d = 0; d < 8; ++d) xa[d] = G2[d] * (y8[d] - m) * rs + C2[d];
            }
        }
        // --- post slot b ---
        {
            h2 o2[4];
#pragma unroll
            for (int h = 0; h < 4; ++h) {
                const float inv = __builtin_amdgcn_rcpf(smb[h]);
                o2[h] = u2h(pku(ob[2*h] * inv, ob[2*h+1] * inv));
            }
            float y[8];
#pragma unroll
            for (int d = 0; d < 8; ++d) {
                const unsigned* w = OW + d*4;
                float a = OB[d];
#pragma unroll
                for (int p = 0; p < 4; ++p) a = fdot2(o2[p], u2h(w[p]), a);
                y[d] = xb[d] + a;
            }
            {
                h2 y2[4];
#pragma unroll
                for (int p = 0; p < 4; ++p) y2[p] = u2h(pku(y[2*p], y[2*p+1]));
                float s1 = 0.f, s2 = 0.f;
#pragma unroll
                for (int p = 0; p < 4; ++p) {
                    s1 = fdot2(y2[p], one2, s1);
                    s2 = fdot2(y2[p], y2[p], s2);
                }
                const float m  = s1 * 0.125f;
                const float v  = fmaf(-m, m, s2 * 0.125f);
                const float rs = __builtin_amdgcn_rsqf(v + 1e-5f);
#pragma unroll
                for (int d = 0; d < 8; ++d) xb[d] = G1[d] * (y[d] - m) * rs + C1[d];
            }
            h2 xx[4];
#pragma unroll
            for (int p = 0; p < 4; ++p) xx[p] = u2h(pku(xb[2*p], xb[2*p+1]));
            float hb[16];
#pragma unroll
            for (int o = 0; o < 16; ++o) {
                const unsigned* w = W1 + o*4;
                float a = B1l[o];
#pragma unroll
                for (int p = 0; p < 4; ++p) a = fdot2(xx[p], u2h(w[p]), a);
                hb[o] = a;
            }
            h2 hp[8];
#pragma unroll
            for (int p = 0; p < 8; ++p) hp[p] = relu2(u2h(pku(hb[2*p], hb[2*p+1])));
            float y8[8];
#pragma unroll
            for (int d = 0; d < 8; ++d) {
                const unsigned* w = W2 + d*8;
                float a = B2l[d];
#pragma unroll
                for (int p = 0; p < 8; ++p) a = fdot2(hp[p], u2h(w[p]), a);
                y8[d] = xb[d] + a;
            }
            {
                h2 y2[4];
#pragma unroll
                for (int p = 0; p < 4; ++p) y2[p] = u2h(pku(y8[2*p], y8[2*p+1]));
                float s1 = 0.f, s2 = 0.f;
#pragma unroll
                for (int p = 0; p < 4; ++p) {
                    s1 = fdot2(y2[p], one2, s1);
                    s2 = fdot2(y2[p], y2[p], s2);
                }
                const float m  = s1 * 0.125f;
                const float v  = fmaf(-m, m, s2 * 0.125f);
                const float rs = __builtin_amdgcn_rsqf(v + 1e-5f);
#pragma unroll
                for (int d = 0; d < 8; ++d) xb[d] = G2[d] * (y8[d] - m) * rs + C2[d];
            }
        }
    }

    // --- floors[seq] = sum over L (butterfly in 16-lane segment), store fp16 ---
#pragma unroll
    for (int d = 0; d < 8; ++d) {
        float t = xa[d];
        t += __shfl_xor(t, 1, 16);
        t += __shfl_xor(t, 2, 16);
        t += __shfl_xor(t, 4, 16);
        t += __shfl_xor(t, 8, 16);
        xa[d] = t;
    }
#pragma unroll
    for (int d = 0; d < 8; ++d) {
        float t = xb[d];
        t += __shfl_xor(t, 1, 16);
        t += __shfl_xor(t, 2, 16);
        t += __shfl_xor(t, 4, 16);
        t += __shfl_xor(t, 8, 16);
        xb[d] = t;
    }
    if (r == 0) {
        union { h8v v; unsigned u[4]; } O;
        O.u[0] = pku(xa[0], xa[1]); O.u[1] = pku(xa[2], xa[3]);
        O.u[2] = pku(xa[4], xa[5]); O.u[3] = pku(xa[6], xa[7]);
        floors_h[seq0] = O.v;
        O.u[0] = pku(xb[0], xb[1]); O.u[1] = pku(xb[2], xb[3]);
        O.u[2] = pku(xb[4], xb[5]); O.u[3] = pku(xb[6], xb[7]);
        floors_h[seq0 + 16] = O.v;
    }
}

// ---------------- K2: per-batch tail (units + match MLP) ----------------
__global__ __launch_bounds__(64) void tail_kernel(
    const int*   __restrict__ cidxs, const int* __restrict__ slots,
    const float* __restrict__ f2,    const float* __restrict__ f3,
    const float* __restrict__ tab_c, const float* __restrict__ tab_s,
    const float* __restrict__ uw,    const float* __restrict__ ub,
    const float* __restrict__ w1,    const float* __restrict__ b1,
    const float* __restrict__ w2,    const float* __restrict__ b2,
    const h8v*   __restrict__ floors_h, float* __restrict__ out)
{
    const int b = blockIdx.x * 64 + threadIdx.x;
    if (b >= B_) return;

    float units[16];
#pragma unroll
    for (int o = 0; o < 16; ++o) units[o] = 0.f;
    for (int fl_i = 0; fl_i < F_; ++fl_i) {
        union { h8v v; _Float16 s[8]; } U;
        U.v = floors_h[(size_t)b * F_ + fl_i];
        float fl[8];
#pragma unroll
        for (int d = 0; d < 8; ++d) fl[d] = (float)U.s[d];
#pragma unroll
        for (int o = 0; o < 16; ++o) {
            float t = ub[o];
#pragma unroll
            for (int d = 0; d < 8; ++d) t += fl[d] * uw[o*8 + d];
            units[o] += fmaxf(t, 0.f);
        }
    }

    float z36[36];
    {
        const int ci = cidxs[b], si = slots[b];
#pragma unroll
        for (int j = 0; j < 8; ++j) z36[j]     = tab_c[(size_t)ci * 8 + j];
#pragma unroll
        for (int j = 0; j < 8; ++j) z36[8 + j] = tab_s[(size_t)si * 8 + j];
#pragma unroll
        for (int j = 0; j < 16; ++j) z36[16 + j] = units[j];
#pragma unroll
        for (int j = 0; j < 4; ++j) z36[32 + j] = f2[(size_t)b * 4 + j];
    }

    float base[20];
#pragma unroll
    for (int o = 0; o < 20; ++o) {
        float t = b1[o];
#pragma unroll
        for (int j = 0; j < 36; ++j) t += z36[j] * w1[o*42 + j];
        base[o] = t;
    }

    const float bb2 = b2[0];
#pragma unroll
    for (int k = 0; k < K_; ++k) {
        float f3v[6];
#pragma unroll
        for (int j = 0; j < 6; ++j) f3v[j] = f3[((size_t)b * K_ + k) * 6 + j];
        float acc = bb2;
#pragma unroll
        for (int o = 0; o < 20; ++o) {
            float t = base[o];
#pragma unroll
            for (int j = 0; j < 6; ++j) t += f3v[j] * w1[o*42 + 36 + j];
            acc += fmaxf(t, 0.f) * w2[o];
        }
        out[(size_t)b * K_ + k] = acc;
    }

    out[(size_t)(B_ * K_) + b] = 4.0f;   // nf3 = K (d_out read as float32)
}

extern "C" void kernel_launch(void* const* d_in, const int* in_sizes, int n_in,
                              void* d_out, int out_size, void* d_ws, size_t ws_size,
                              hipStream_t stream)
{
    const int*   cidxs  = (const int*)  d_in[0];
    const int*   slots  = (const int*)  d_in[1];
    const float* gfeats = (const float*)d_in[2];
    const float* f2     = (const float*)d_in[3];
    const float* f3     = (const float*)d_in[4];
    const float* tab_c  = (const float*)d_in[5];
    const float* tab_s  = (const float*)d_in[6];
    const float* fw     = (const float*)d_in[7];
    const float* fb     = (const float*)d_in[8];
    const float* ipw    = (const float*)d_in[9];
    const float* ipb    = (const float*)d_in[10];
    const float* ow     = (const float*)d_in[11];
    const float* ob     = (const float*)d_in[12];
    const float* l1w    = (const float*)d_in[13];
    const float* l1b    = (const float*)d_in[14];
    const float* l2w    = (const float*)d_in[15];
    const float* l2b    = (const float*)d_in[16];
    const float* n1g    = (const float*)d_in[17];
    const float* n1b    = (const float*)d_in[18];
    const float* n2g    = (const float*)d_in[19];
    const float* n2b    = (const float*)d_in[20];
    const float* uw     = (const float*)d_in[21];
    const float* ub     = (const float*)d_in[22];
    const float* w1     = (const float*)d_in[23];
    const float* b1     = (const float*)d_in[24];
    const float* w2     = (const float*)d_in[25];
    const float* b2     = (const float*)d_in[26];

    unsigned* ws       = (unsigned*)d_ws;
    h8v*      floors_h = (h8v*)((char*)d_ws + FLOORS_OFF);

    cvt_weights<<<1, 256, 0, stream>>>(fw, ipw, ow, l1w, l2w,
                                       fb, ipb, ob, l1b, l2b,
                                       n1g, n1b, n2g, n2b, ws);

    seq_kernel<<<SEQS_ / 32, 256, 0, stream>>>(gfeats, ws);

    tail_kernel<<<B_ / 64, 64, 0, stream>>>(
        cidxs, slots, f2, f3, tab_c, tab_s, uw, ub, w1, b1, w2, b2,
        floors_h, (float*)d_out);
}

// Round 11
// 242.229 us; speedup vs baseline: 4.5141x; 1.7553x over previous
//
#include <hip/hip_runtime.h>

// Problem constants
#define B_    16384
#define F_    8
#define L_    16
#define K_    4
#define SEQS_ (B_ * F_)   // 131072

// log2(e) / sqrt(2): folded into Wq/bq at convert time
#define SCORE_SCALE 1.02040774484936f

typedef _Float16 h2  __attribute__((ext_vector_type(2)));
typedef _Float16 h8v __attribute__((ext_vector_type(8)));

#if __has_builtin(__builtin_amdgcn_fdot2)
__device__ __forceinline__ float fdot2(h2 a, h2 b, float c) {
    return __builtin_amdgcn_fdot2(a, b, c, false);   // v_dot2_f32_f16
}
#else
__device__ __forceinline__ float fdot2(h2 a, h2 b, float c) {
    return c + (float)a[0] * (float)b[0] + (float)a[1] * (float)b[1];
}
#endif

__device__ __forceinline__ unsigned pku(float a, float b) {
    return __builtin_bit_cast(unsigned, __builtin_amdgcn_cvt_pkrtz(a, b));
}
__device__ __forceinline__ h2 u2h(unsigned u) {
    return __builtin_bit_cast(h2, u);
}
__device__ __forceinline__ h2 relu2(h2 a) {
#if __has_builtin(__builtin_elementwise_max)
    h2 z = {(_Float16)0.f, (_Float16)0.f};
    return __builtin_elementwise_max(a, z);          // v_pk_max_f16
#else
    h2 r; r[0] = a[0] > (_Float16)0.f ? a[0] : (_Float16)0.f;
          r[1] = a[1] > (_Float16)0.f ? a[1] : (_Float16)0.f;
    return r;
#endif
}

// ---- ws layout (all weights+biases merged; staged to LDS in seq_kernel) ----
#define WOFF_FW   0
#define WOFF_IPW  16
#define WOFF_OW   304
#define WOFF_L1W  400
#define WOFF_L2W  592
#define NW_U      784
#define BOFF_FB   0
#define BOFF_IPB  8
#define BOFF_OB   80
#define BOFF_L1B  104
#define BOFF_L2B  152
#define BOFF_N1G  176
#define BOFF_N1B  200
#define BOFF_N2G  224
#define BOFF_N2B  248
#define NB_F      272
#define FLOORS_OFF 8192

// ---------------- K0: pack weights fp32 -> h2 pairs, copy biases ----------------
__global__ __launch_bounds__(256) void cvt_weights(
    const float* __restrict__ fw,  const float* __restrict__ ipw,
    const float* __restrict__ ow,  const float* __restrict__ l1w,
    const float* __restrict__ l2w,
    const float* __restrict__ fb,  const float* __restrict__ ipb,
    const float* __restrict__ ob,  const float* __restrict__ l1b,
    const float* __restrict__ l2b,
    const float* __restrict__ n1g, const float* __restrict__ n1b,
    const float* __restrict__ n2g, const float* __restrict__ n2b,
    unsigned* __restrict__ ws)
{
    // weights (pairwise pack; q-rows of ipw get SCORE_SCALE folded in)
    for (int i = threadIdx.x; i < NW_U; i += 256) {
        const float* s; int off; float scale = 1.f;
        if (i < WOFF_IPW)      { s = fw;  off = i; }
        else if (i < WOFF_OW)  { s = ipw; off = i - WOFF_IPW;
                                 if (((off % 96) >> 2) < 8) scale = SCORE_SCALE; }
        else if (i < WOFF_L1W) { s = ow;  off = i - WOFF_OW; }
        else if (i < WOFF_L2W) { s = l1w; off = i - WOFF_L1W; }
        else                   { s = l2w; off = i - WOFF_L2W; }
        ws[i] = pku(s[2*off] * scale, s[2*off + 1] * scale);
    }
    // biases / LN params (fp32 copy; q-rows of ipb scaled)
    float* bias = (float*)(ws + NW_U);
    for (int i = threadIdx.x; i < NB_F; i += 256) {
        float v;
        if (i < BOFF_IPB)      v = fb[i];
        else if (i < BOFF_OB)  { int j = i - BOFF_IPB; v = ipb[j];
                                 if ((j % 24) < 8) v *= SCORE_SCALE; }
        else if (i < BOFF_L1B) v = ob[i - BOFF_OB];
        else if (i < BOFF_L2B) v = l1b[i - BOFF_L1B];
        else if (i < BOFF_N1G) v = l2b[i - BOFF_L2B];
        else if (i < BOFF_N1B) v = n1g[i - BOFF_N1G];
        else if (i < BOFF_N2G) v = n1b[i - BOFF_N1B];
        else if (i < BOFF_N2B) v = n2g[i - BOFF_N2G];
        else                   v = n2b[i - BOFF_N2B];
        bias[i] = v;
    }
}

// ---------------- K1: per-sequence transformer, 2 sequences per group ----------------
// 16 lanes per group; each group runs TWO sequences (a = seq0, b = seq0+16).
// Straight-line duplicated code (no lambdas, no [slot] arrays) so SROA promotes
// everything. launch_bounds (256,4): 128-VGPR budget so the ~100-reg peak of
// the dual-sequence body fits WITHOUT spilling (R7/R9/R10 post-mortem: the
// (256,6) 85-reg budget forced scratch).
__global__ __launch_bounds__(256, 4) void seq_kernel(
    const float* __restrict__ gfeats,
    const unsigned* __restrict__ ws)
{
    // kb: row r, col = g*2 + slot (32 cols). Stride 33 uint4 = 528 B/row:
    // writes 2-way bank aliased (free), reads 4-address broadcast (free).
    __shared__ uint4 kb[16][33];
    // vt: slot base s*1088 dw + g*68; [jp][d] h2-over-j-pairs + 4 pad.
    __shared__ unsigned vt_dw[2 * 16 * 68];
    // staged weights + biases (uniform; broadcast reads, 0 conflicts)
    __shared__ unsigned wlds[NW_U + NB_F];

    for (int i = threadIdx.x; i < NW_U + NB_F; i += 256) wlds[i] = ws[i];
    __syncthreads();

    const unsigned* wq  = wlds;
    const float* bias   = (const float*)(wlds + NW_U);
    h8v* floors_h       = (h8v*)((char*)ws + FLOORS_OFF);

    const int tid = threadIdx.x;
    const int g   = tid >> 4;   // group within block (0..15)
    const int r   = tid & 15;   // row within sequence
    const int seq0 = blockIdx.x * 32 + g;      // slot a; slot b = seq0 + 16

    _Float16* vth  = (_Float16*)vt_dw;
    const int vwrA = g*136 + (r>>1)*16 + (r&1); // halfword write base, slot a
    const int vwrB = vwrA + 2176;               // slot b (+1088 dwords)
    const int vrdA = g*68;                      // dword read base, slot a
    const int vrdB = vrdA + 1088;
    const int colA = g*2, colB = g*2 + 1;

    const h2 one2 = u2h(0x3C003C00u);

    // --- emb_floor: x = feat @ fw.T + fb (both slots) ---
    float xa[8], xb[8];
    {
        const float4 f = *reinterpret_cast<const float4*>(gfeats + ((size_t)seq0 * L_ + r) * 4);
        const h2 f0 = u2h(pku(f.x, f.y)), f1 = u2h(pku(f.z, f.w));
#pragma unroll
        for (int d = 0; d < 8; ++d)
            xa[d] = fdot2(f0, u2h(wq[WOFF_FW + d*2]),
                    fdot2(f1, u2h(wq[WOFF_FW + d*2 + 1]), bias[BOFF_FB + d]));
    }
    {
        const float4 f = *reinterpret_cast<const float4*>(gfeats + ((size_t)(seq0 + 16) * L_ + r) * 4);
        const h2 f0 = u2h(pku(f.x, f.y)), f1 = u2h(pku(f.z, f.w));
#pragma unroll
        for (int d = 0; d < 8; ++d)
            xb[d] = fdot2(f0, u2h(wq[WOFF_FW + d*2]),
                    fdot2(f1, u2h(wq[WOFF_FW + d*2 + 1]), bias[BOFF_FB + d]));
    }

#pragma unroll
    for (int li = 0; li < 3; ++li) {
        const unsigned* W  = wq + WOFF_IPW + li * 96;   // 24 rows x 4 h2
        const float*    Bq = bias + BOFF_IPB + li * 24;

        h2 xa2[4], xb2[4];
#pragma unroll
        for (int p = 0; p < 4; ++p) {
            xa2[p] = u2h(pku(xa[2*p], xa[2*p+1]));
            xb2[p] = u2h(pku(xb[2*p], xb[2*p+1]));
        }

        // k -> packed fp16 LDS (each weight read shared by both slots)
        {
            float ka[8], kc[8];
#pragma unroll
            for (int o = 0; o < 8; ++o) {
                const unsigned* w = W + (8 + o)*4;
                const float bq = Bq[8 + o];
                float aa = bq, ab = bq;
#pragma unroll
                for (int p = 0; p < 4; ++p) {
                    const h2 wp = u2h(w[p]);
                    aa = fdot2(xa2[p], wp, aa);
                    ab = fdot2(xb2[p], wp, ab);
                }
                ka[o] = aa; kc[o] = ab;
            }
            uint4 Kp;
            Kp.x = pku(ka[0], ka[1]); Kp.y = pku(ka[2], ka[3]);
            Kp.z = pku(ka[4], ka[5]); Kp.w = pku(ka[6], ka[7]);
            kb[r][colA] = Kp;
            Kp.x = pku(kc[0], kc[1]); Kp.y = pku(kc[2], kc[3]);
            Kp.z = pku(kc[4], kc[5]); Kp.w = pku(kc[6], kc[7]);
            kb[r][colB] = Kp;
        }
        // v -> fp16 pair-transposed LDS (halfword scatter, both slots)
        {
#pragma unroll
            for (int o = 0; o < 8; ++o) {
                const unsigned* w = W + (16 + o)*4;
                const float bq = Bq[16 + o];
                float aa = bq, ab = bq;
#pragma unroll
                for (int p = 0; p < 4; ++p) {
                    const h2 wp = u2h(w[p]);
                    aa = fdot2(xa2[p], wp, aa);
                    ab = fdot2(xb2[p], wp, ab);
                }
                vth[vwrA + 2*o] = (_Float16)aa;
                vth[vwrB + 2*o] = (_Float16)ab;
            }
        }
        // q last (scale pre-folded into W/B): hides the k/v write->read gap
        h2 qa[4], qb[4];
#pragma unroll
        for (int h = 0; h < 4; ++h) {
            const unsigned* w0 = W + (2*h)*4;
            const unsigned* w1 = W + (2*h+1)*4;
            float a0 = Bq[2*h], a1 = Bq[2*h+1];
            float b0 = a0, b1 = a1;
#pragma unroll
            for (int p = 0; p < 4; ++p) {
                const h2 wp0 = u2h(w0[p]);
                const h2 wp1 = u2h(w1[p]);
                a0 = fdot2(xa2[p], wp0, a0);
                a1 = fdot2(xa2[p], wp1, a1);
                b0 = fdot2(xb2[p], wp0, b0);
                b1 = fdot2(xb2[p], wp1, b1);
            }
            qa[h] = u2h(pku(a0, a1));
            qb[h] = u2h(pku(b0, b1));
        }
        // No __syncthreads: each (slot, group) LDS region is wave-private; DS
        // ops are in-order per wave.

        // --- attention slot a ---
        float oa[8] = {0.f,0.f,0.f,0.f,0.f,0.f,0.f,0.f};
        float sma[4] = {0.f,0.f,0.f,0.f};
#pragma unroll
        for (int jp = 0; jp < 8; ++jp) {
            const uint4 Ka = kb[2*jp][colA];
            const uint4 Kb = kb[2*jp + 1][colA];
            const uint4 va = *reinterpret_cast<const uint4*>(&vt_dw[vrdA + jp*8]);
            const uint4 vb = *reinterpret_cast<const uint4*>(&vt_dw[vrdA + jp*8 + 4]);
            const float pa0 = __builtin_amdgcn_exp2f(fdot2(qa[0], u2h(Ka.x), 0.f));
            const float pa1 = __builtin_amdgcn_exp2f(fdot2(qa[1], u2h(Ka.y), 0.f));
            const float pa2 = __builtin_amdgcn_exp2f(fdot2(qa[2], u2h(Ka.z), 0.f));
            const float pa3 = __builtin_amdgcn_exp2f(fdot2(qa[3], u2h(Ka.w), 0.f));
            const float pb0 = __builtin_amdgcn_exp2f(fdot2(qa[0], u2h(Kb.x), 0.f));
            const float pb1 = __builtin_amdgcn_exp2f(fdot2(qa[1], u2h(Kb.y), 0.f));
            const float pb2 = __builtin_amdgcn_exp2f(fdot2(qa[2], u2h(Kb.z), 0.f));
            const float pb3 = __builtin_amdgcn_exp2f(fdot2(qa[3], u2h(Kb.w), 0.f));
            const h2 pp0 = u2h(pku(pa0, pb0));
            const h2 pp1 = u2h(pku(pa1, pb1));
            const h2 pp2 = u2h(pku(pa2, pb2));
            const h2 pp3 = u2h(pku(pa3, pb3));
            sma[0] = fdot2(pp0, one2, sma[0]);
            sma[1] = fdot2(pp1, one2, sma[1]);
            sma[2] = fdot2(pp2, one2, sma[2]);
            sma[3] = fdot2(pp3, one2, sma[3]);
            oa[0] = fdot2(pp0, u2h(va.x), oa[0]);
            oa[1] = fdot2(pp0, u2h(va.y), oa[1]);
            oa[2] = fdot2(pp1, u2h(va.z), oa[2]);
            oa[3] = fdot2(pp1, u2h(va.w), oa[3]);
            oa[4] = fdot2(pp2, u2h(vb.x), oa[4]);
            oa[5] = fdot2(pp2, u2h(vb.y), oa[5]);
            oa[6] = fdot2(pp3, u2h(vb.z), oa[6]);
            oa[7] = fdot2(pp3, u2h(vb.w), oa[7]);
        }
        // --- attention slot b ---
        float ob[8] = {0.f,0.f,0.f,0.f,0.f,0.f,0.f,0.f};
        float smb[4] = {0.f,0.f,0.f,0.f};
#pragma unroll
        for (int jp = 0; jp < 8; ++jp) {
            const uint4 Ka = kb[2*jp][colB];
            const uint4 Kb = kb[2*jp + 1][colB];
            const uint4 va = *reinterpret_cast<const uint4*>(&vt_dw[vrdB + jp*8]);
            const uint4 vb = *reinterpret_cast<const uint4*>(&vt_dw[vrdB + jp*8 + 4]);
            const float pa0 = __builtin_amdgcn_exp2f(fdot2(qb[0], u2h(Ka.x), 0.f));
            const float pa1 = __builtin_amdgcn_exp2f(fdot2(qb[1], u2h(Ka.y), 0.f));
            const float pa2 = __builtin_amdgcn_exp2f(fdot2(qb[2], u2h(Ka.z), 0.f));
            const float pa3 = __builtin_amdgcn_exp2f(fdot2(qb[3], u2h(Ka.w), 0.f));
            const float pb0 = __builtin_amdgcn_exp2f(fdot2(qb[0], u2h(Kb.x), 0.f));
            const float pb1 = __builtin_amdgcn_exp2f(fdot2(qb[1], u2h(Kb.y), 0.f));
            const float pb2 = __builtin_amdgcn_exp2f(fdot2(qb[2], u2h(Kb.z), 0.f));
            const float pb3 = __builtin_amdgcn_exp2f(fdot2(qb[3], u2h(Kb.w), 0.f));
            const h2 pp0 = u2h(pku(pa0, pb0));
            const h2 pp1 = u2h(pku(pa1, pb1));
            const h2 pp2 = u2h(pku(pa2, pb2));
            const h2 pp3 = u2h(pku(pa3, pb3));
            smb[0] = fdot2(pp0, one2, smb[0]);
            smb[1] = fdot2(pp1, one2, smb[1]);
            smb[2] = fdot2(pp2, one2, smb[2]);
            smb[3] = fdot2(pp3, one2, smb[3]);
            ob[0] = fdot2(pp0, u2h(va.x), ob[0]);
            ob[1] = fdot2(pp0, u2h(va.y), ob[1]);
            ob[2] = fdot2(pp1, u2h(va.z), ob[2]);
            ob[3] = fdot2(pp1, u2h(va.w), ob[3]);
            ob[4] = fdot2(pp2, u2h(vb.x), ob[4]);
            ob[5] = fdot2(pp2, u2h(vb.y), ob[5]);
            ob[6] = fdot2(pp3, u2h(vb.z), ob[6]);
            ob[7] = fdot2(pp3, u2h(vb.w), ob[7]);
        }

        const unsigned* OW  = wq + WOFF_OW + li * 32;
        const float*    OB  = bias + BOFF_OB + li * 8;
        const unsigned* W1  = wq + WOFF_L1W + li * 64;
        const float*    B1l = bias + BOFF_L1B + li * 16;
        const unsigned* W2  = wq + WOFF_L2W + li * 64;
        const float*    B2l = bias + BOFF_L2B + li * 8;
        const float* G1 = bias + BOFF_N1G + li * 8;
        const float* C1 = bias + BOFF_N1B + li * 8;
        const float* G2 = bias + BOFF_N2G + li * 8;
        const float* C2 = bias + BOFF_N2B + li * 8;

        // --- post slot a: out-proj + residual + LN1 + FFN + LN2 ---
        {
            h2 o2[4];
#pragma unroll
            for (int h = 0; h < 4; ++h) {
                const float inv = __builtin_amdgcn_rcpf(sma[h]);
                o2[h] = u2h(pku(oa[2*h] * inv, oa[2*h+1] * inv));
            }
            float y[8];
#pragma unroll
            for (int d = 0; d < 8; ++d) {
                const unsigned* w = OW + d*4;
                float a = OB[d];
#pragma unroll
                for (int p = 0; p < 4; ++p) a = fdot2(o2[p], u2h(w[p]), a);
                y[d] = xa[d] + a;
            }
            {
                h2 y2[4];
#pragma unroll
                for (int p = 0; p < 4; ++p) y2[p] = u2h(pku(y[2*p], y[2*p+1]));
                float s1 = 0.f, s2 = 0.f;
#pragma unroll
                for (int p = 0; p < 4; ++p) {
                    s1 = fdot2(y2[p], one2, s1);
                    s2 = fdot2(y2[p], y2[p], s2);
                }
                const float m  = s1 * 0.125f;
                const float v  = fmaf(-m, m, s2 * 0.125f);
                const float rs = __builtin_amdgcn_rsqf(v + 1e-5f);
#pragma unroll
                for (int d = 0; d < 8; ++d) xa[d] = G1[d] * (y[d] - m) * rs + C1[d];
            }
            h2 xx[4];
#pragma unroll
            for (int p = 0; p < 4; ++p) xx[p] = u2h(pku(xa[2*p], xa[2*p+1]));
            float hb[16];
#pragma unroll
            for (int o = 0; o < 16; ++o) {
                const unsigned* w = W1 + o*4;
                float a = B1l[o];
#pragma unroll
                for (int p = 0; p < 4; ++p) a = fdot2(xx[p], u2h(w[p]), a);
                hb[o] = a;
            }
            h2 hp[8];
#pragma unroll
            for (int p = 0; p < 8; ++p) hp[p] = relu2(u2h(pku(hb[2*p], hb[2*p+1])));
            float y8[8];
#pragma unroll
            for (int d = 0; d < 8; ++d) {
                const unsigned* w = W2 + d*8;
                float a = B2l[d];
#pragma unroll
                for (int p = 0; p < 8; ++p) a = fdot2(hp[p], u2h(w[p]), a);
                y8[d] = xa[d] + a;
            }
            {
                h2 y2[4];
#pragma unroll
                for (int p = 0; p < 4; ++p) y2[p] = u2h(pku(y8[2*p], y8[2*p+1]));
                float s1 = 0.f, s2 = 0.f;
#pragma unroll
                for (int p = 0; p < 4; ++p) {
                    s1 = fdot2(y2[p], one2, s1);
                    s2 = fdot2(y2[p], y2[p], s2);
                }
                const float m  = s1 * 0.125f;
                const float v  = fmaf(-m, m, s2 * 0.125f);
                const float rs = __builtin_amdgcn_rsqf(v + 1e-5f);
#pragma unroll
                for (int d = 0; d < 8; ++d) xa[d] = G2[d] * (y8[d] - m) * rs + C2[d];
            }
        }
        // --- post slot b ---
        {
            h2 o2[4];
#pragma unroll
            for (int h = 0; h < 4; ++h) {
                const float inv = __builtin_amdgcn_rcpf(smb[h]);
                o2[h] = u2h(pku(ob[2*h] * inv, ob[2*h+1] * inv));
            }
            float y[8];
#pragma unroll
            for (int d = 0; d < 8; ++d) {
                const unsigned* w = OW + d*4;
                float a = OB[d];
#pragma unroll
                for (int p = 0; p < 4; ++p) a = fdot2(o2[p], u2h(w[p]), a);
                y[d] = xb[d] + a;
            }
            {
                h2 y2[4];
#pragma unroll
                for (int p = 0; p < 4; ++p) y2[p] = u2h(pku(y[2*p], y[2*p+1]));
                float s1 = 0.f, s2 = 0.f;
#pragma unroll
                for (int p = 0; p < 4; ++p) {
                    s1 = fdot2(y2[p], one2, s1);
                    s2 = fdot2(y2[p], y2[p], s2);
                }
                const float m  = s1 * 0.125f;
                const float v  = fmaf(-m, m, s2 * 0.125f);
                const float rs = __builtin_amdgcn_rsqf(v + 1e-5f);
#pragma unroll
                for (int d = 0; d < 8; ++d) xb[d] = G1[d] * (y[d] - m) * rs + C1[d];
            }
            h2 xx[4];
#pragma unroll
            for (int p = 0; p < 4; ++p) xx[p] = u2h(pku(xb[2*p], xb[2*p+1]));
            float hb[16];
#pragma unroll
            for (int o = 0; o < 16; ++o) {
                const unsigned* w = W1 + o*4;
                float a = B1l[o];
#pragma unroll
                for (int p = 0; p < 4; ++p) a = fdot2(xx[p], u2h(w[p]), a);
                hb[o] = a;
            }
            h2 hp[8];
#pragma unroll
            for (int p = 0; p < 8; ++p) hp[p] = relu2(u2h(pku(hb[2*p], hb[2*p+1])));
            float y8[8];
#pragma unroll
            for (int d = 0; d < 8; ++d) {
                const unsigned* w = W2 + d*8;
                float a = B2l[d];
#pragma unroll
                for (int p = 0; p < 8; ++p) a = fdot2(hp[p], u2h(w[p]), a);
                y8[d] = xb[d] + a;
            }
            {
                h2 y2[4];
#pragma unroll
                for (int p = 0; p < 4; ++p) y2[p] = u2h(pku(y8[2*p], y8[2*p+1]));
                float s1 = 0.f, s2 = 0.f;
#pragma unroll
                for (int p = 0; p < 4; ++p) {
                    s1 = fdot2(y2[p], one2, s1);
                    s2 = fdot2(y2[p], y2[p], s2);
                }
                const float m  = s1 * 0.125f;
                const float v  = fmaf(-m, m, s2 * 0.125f);
                const float rs = __builtin_amdgcn_rsqf(v + 1e-5f);
#pragma unroll
                for (int d = 0; d < 8; ++d) xb[d] = G2[d] * (y8[d] - m) * rs + C2[d];
            }
        }
    }

    // --- floors[seq] = sum over L (butterfly in 16-lane segment), store fp16 ---
#pragma unroll
    for (int d = 0; d < 8; ++d) {
        float t = xa[d];
        t += __shfl_xor(t, 1, 16);
        t += __shfl_xor(t, 2, 16);
        t += __shfl_xor(t, 4, 16);
        t += __shfl_xor(t, 8, 16);
        xa[d] = t;
    }
#pragma unroll
    for (int d = 0; d < 8; ++d) {
        float t = xb[d];
        t += __shfl_xor(t, 1, 16);
        t += __shfl_xor(t, 2, 16);
        t += __shfl_xor(t, 4, 16);
        t += __shfl_xor(t, 8, 16);
        xb[d] = t;
    }
    if (r == 0) {
        union { h8v v; unsigned u[4]; } O;
        O.u[0] = pku(xa[0], xa[1]); O.u[1] = pku(xa[2], xa[3]);
        O.u[2] = pku(xa[4], xa[5]); O.u[3] = pku(xa[6], xa[7]);
        floors_h[seq0] = O.v;
        O.u[0] = pku(xb[0], xb[1]); O.u[1] = pku(xb[2], xb[3]);
        O.u[2] = pku(xb[4], xb[5]); O.u[3] = pku(xb[6], xb[7]);
        floors_h[seq0 + 16] = O.v;
    }
}

// ---------------- K2: per-batch tail (units + match MLP) ----------------
__global__ __launch_bounds__(64) void tail_kernel(
    const int*   __restrict__ cidxs, const int* __restrict__ slots,
    const float* __restrict__ f2,    const float* __restrict__ f3,
    const float* __restrict__ tab_c, const float* __restrict__ tab_s,
    const float* __restrict__ uw,    const float* __restrict__ ub,
    const float* __restrict__ w1,    const float* __restrict__ b1,
    const float* __restrict__ w2,    const float* __restrict__ b2,
    const h8v*   __restrict__ floors_h, float* __restrict__ out)
{
    const int b = blockIdx.x * 64 + threadIdx.x;
    if (b >= B_) return;

    float units[16];
#pragma unroll
    for (int o = 0; o < 16; ++o) units[o] = 0.f;
    for (int fl_i = 0; fl_i < F_; ++fl_i) {
        union { h8v v; _Float16 s[8]; } U;
        U.v = floors_h[(size_t)b * F_ + fl_i];
        float fl[8];
#pragma unroll
        for (int d = 0; d < 8; ++d) fl[d] = (float)U.s[d];
#pragma unroll
        for (int o = 0; o < 16; ++o) {
            float t = ub[o];
#pragma unroll
            for (int d = 0; d < 8; ++d) t += fl[d] * uw[o*8 + d];
            units[o] += fmaxf(t, 0.f);
        }
    }

    float z36[36];
    {
        const int ci = cidxs[b], si = slots[b];
#pragma unroll
        for (int j = 0; j < 8; ++j) z36[j]     = tab_c[(size_t)ci * 8 + j];
#pragma unroll
        for (int j = 0; j < 8; ++j) z36[8 + j] = tab_s[(size_t)si * 8 + j];
#pragma unroll
        for (int j = 0; j < 16; ++j) z36[16 + j] = units[j];
#pragma unroll
        for (int j = 0; j < 4; ++j) z36[32 + j] = f2[(size_t)b * 4 + j];
    }

    float base[20];
#pragma unroll
    for (int o = 0; o < 20; ++o) {
        float t = b1[o];
#pragma unroll
        for (int j = 0; j < 36; ++j) t += z36[j] * w1[o*42 + j];
        base[o] = t;
    }

    const float bb2 = b2[0];
#pragma unroll
    for (int k = 0; k < K_; ++k) {
        float f3v[6];
#pragma unroll
        for (int j = 0; j < 6; ++j) f3v[j] = f3[((size_t)b * K_ + k) * 6 + j];
        float acc = bb2;
#pragma unroll
        for (int o = 0; o < 20; ++o) {
            float t = base[o];
#pragma unroll
            for (int j = 0; j < 6; ++j) t += f3v[j] * w1[o*42 + 36 + j];
            acc += fmaxf(t, 0.f) * w2[o];
        }
        out[(size_t)b * K_ + k] = acc;
    }

    out[(size_t)(B_ * K_) + b] = 4.0f;   // nf3 = K (d_out read as float32)
}

extern "C" void kernel_launch(void* const* d_in, const int* in_sizes, int n_in,
                              void* d_out, int out_size, void* d_ws, size_t ws_size,
                              hipStream_t stream)
{
    const int*   cidxs  = (const int*)  d_in[0];
    const int*   slots  = (const int*)  d_in[1];
    const float* gfeats = (const float*)d_in[2];
    const float* f2     = (const float*)d_in[3];
    const float* f3     = (const float*)d_in[4];
    const float* tab_c  = (const float*)d_in[5];
    const float* tab_s  = (const float*)d_in[6];
    const float* fw     = (const float*)d_in[7];
    const float* fb     = (const float*)d_in[8];
    const float* ipw    = (const float*)d_in[9];
    const float* ipb    = (const float*)d_in[10];
    const float* ow     = (const float*)d_in[11];
    const float* ob     = (const float*)d_in[12];
    const float* l1w    = (const float*)d_in[13];
    const float* l1b    = (const float*)d_in[14];
    const float* l2w    = (const float*)d_in[15];
    const float* l2b    = (const float*)d_in[16];
    const float* n1g    = (const float*)d_in[17];
    const float* n1b    = (const float*)d_in[18];
    const float* n2g    = (const float*)d_in[19];
    const float* n2b    = (const float*)d_in[20];
    const float* uw     = (const float*)d_in[21];
    const float* ub     = (const float*)d_in[22];
    const float* w1     = (const float*)d_in[23];
    const float* b1     = (const float*)d_in[24];
    const float* w2     = (const float*)d_in[25];
    const float* b2     = (const float*)d_in[26];

    unsigned* ws       = (unsigned*)d_ws;
    h8v*      floors_h = (h8v*)((char*)d_ws + FLOORS_OFF);

    cvt_weights<<<1, 256, 0, stream>>>(fw, ipw, ow, l1w, l2w,
                                       fb, ipb, ob, l1b, l2b,
                                       n1g, n1b, n2g, n2b, ws);

    seq_kernel<<<SEQS_ / 32, 256, 0, stream>>>(gfeats, ws);

    tail_kernel<<<B_ / 64, 64, 0, stream>>>(
        cidxs, slots, f2, f3, tab_c, tab_s, uw, ub, w1, b1, w2, b2,
        floors_h, (float*)d_out);
}

// Round 12
// 154.980 us; speedup vs baseline: 7.0554x; 1.5630x over previous
//
#include <hip/hip_runtime.h>

// Problem constants
#define B_    16384
#define F_    8
#define L_    16
#define K_    4
#define SEQS_ (B_ * F_)   // 131072

// log2(e) / sqrt(2): folded into Wq/bq at convert time
#define SCORE_SCALE 1.02040774484936f

typedef _Float16 h2  __attribute__((ext_vector_type(2)));

#if __has_builtin(__builtin_amdgcn_fdot2)
__device__ __forceinline__ float fdot2(h2 a, h2 b, float c) {
    return __builtin_amdgcn_fdot2(a, b, c, false);   // v_dot2_f32_f16
}
#else
__device__ __forceinline__ float fdot2(h2 a, h2 b, float c) {
    return c + (float)a[0] * (float)b[0] + (float)a[1] * (float)b[1];
}
#endif

__device__ __forceinline__ unsigned pku(float a, float b) {
    return __builtin_bit_cast(unsigned, __builtin_amdgcn_cvt_pkrtz(a, b));
}
__device__ __forceinline__ h2 u2h(unsigned u) {
    return __builtin_bit_cast(h2, u);
}
__device__ __forceinline__ h2 relu2(h2 a) {
#if __has_builtin(__builtin_elementwise_max)
    h2 z = {(_Float16)0.f, (_Float16)0.f};
    return __builtin_elementwise_max(a, z);          // v_pk_max_f16
#else
    h2 r; r[0] = a[0] > (_Float16)0.f ? a[0] : (_Float16)0.f;
          r[1] = a[1] > (_Float16)0.f ? a[1] : (_Float16)0.f;
    return r;
#endif
}

// ---- LDS weight-blob layout (packed h2 weights, then fp32 biases/LN) ----
#define WOFF_FW   0
#define WOFF_IPW  16
#define WOFF_OW   304
#define WOFF_L1W  400
#define WOFF_L2W  592
#define NW_U      784
#define BOFF_FB   0
#define BOFF_IPB  8
#define BOFF_OB   80
#define BOFF_L1B  104
#define BOFF_L2B  152
#define BOFF_N1G  176
#define BOFF_N1B  200
#define BOFF_N2G  224
#define BOFF_N2B  248
#define NB_F      272

// ---------------- single fused kernel ----------------
// 16 lanes per sequence, 16 sequences per 256-thread block = exactly 2 batches
// (16 = 2 * F). Weights converted+staged to LDS per block; transformer runs as
// the proven R8 body; floors land in LDS; the tail (units + match MLP) runs
// in-block. One launch total.
__global__ __launch_bounds__(256, 8) void fused_kernel(
    const float* __restrict__ gfeats,
    const float* __restrict__ fw,  const float* __restrict__ ipw,
    const float* __restrict__ ow,  const float* __restrict__ l1w,
    const float* __restrict__ l2w,
    const float* __restrict__ fb,  const float* __restrict__ ipb,
    const float* __restrict__ ob,  const float* __restrict__ l1b,
    const float* __restrict__ l2b,
    const float* __restrict__ n1g, const float* __restrict__ n1b,
    const float* __restrict__ n2g, const float* __restrict__ n2b,
    const int*   __restrict__ cidxs, const int* __restrict__ slots,
    const float* __restrict__ f2,    const float* __restrict__ f3,
    const float* __restrict__ tab_c, const float* __restrict__ tab_s,
    const float* __restrict__ uw,    const float* __restrict__ ub,
    const float* __restrict__ w1,    const float* __restrict__ b1,
    const float* __restrict__ w2,    const float* __restrict__ b2,
    float* __restrict__ out)
{
    __shared__ uint4 kb[16][17];          // K tiles (R8-proven layout)
    __shared__ unsigned vt_dw[16 * 68];   // V pair-transposed
    __shared__ unsigned wlds[NW_U + NB_F];
    __shared__ float floors_lds[16][8];   // fp32 floors (2 batches x 8 floors)
    __shared__ float units_lds[2][16];
    __shared__ float pm_lds[2][4][20];    // match-MLP partials

    const int tid = threadIdx.x;

    // --- stage weights: convert fp32 -> packed h2 inline (per block) ---
    for (int i = tid; i < NW_U; i += 256) {
        const float* s; int off; float scale = 1.f;
        if (i < WOFF_IPW)      { s = fw;  off = i; }
        else if (i < WOFF_OW)  { s = ipw; off = i - WOFF_IPW;
                                 if (((off % 96) >> 2) < 8) scale = SCORE_SCALE; }
        else if (i < WOFF_L1W) { s = ow;  off = i - WOFF_OW; }
        else if (i < WOFF_L2W) { s = l1w; off = i - WOFF_L1W; }
        else                   { s = l2w; off = i - WOFF_L2W; }
        wlds[i] = pku(s[2*off] * scale, s[2*off + 1] * scale);
    }
    {
        float* bdst = (float*)(wlds + NW_U);
        for (int i = tid; i < NB_F; i += 256) {
            float v;
            if (i < BOFF_IPB)      v = fb[i];
            else if (i < BOFF_OB)  { int j = i - BOFF_IPB; v = ipb[j];
                                     if ((j % 24) < 8) v *= SCORE_SCALE; }
            else if (i < BOFF_L1B) v = ob[i - BOFF_OB];
            else if (i < BOFF_L2B) v = l1b[i - BOFF_L1B];
            else if (i < BOFF_N1G) v = l2b[i - BOFF_L2B];
            else if (i < BOFF_N1B) v = n1g[i - BOFF_N1G];
            else if (i < BOFF_N2G) v = n1b[i - BOFF_N1B];
            else if (i < BOFF_N2B) v = n2g[i - BOFF_N2G];
            else                   v = n2b[i - BOFF_N2B];
            bdst[i] = v;
        }
    }
    __syncthreads();

    const unsigned* wq  = wlds;
    const float* bias   = (const float*)(wlds + NW_U);

    const int g   = tid >> 4;   // group within block (0..15)
    const int r   = tid & 15;   // row within sequence
    const int seq = blockIdx.x * 16 + g;

    _Float16* vth = (_Float16*)vt_dw;
    const int vwr = g*136 + (r>>1)*16 + (r&1);  // halfword write base
    const int vrd = g*68;                       // dword read base

    // --- emb_floor: x = feat @ fw.T + fb ---
    const float4 f = *reinterpret_cast<const float4*>(gfeats + ((size_t)seq * L_ + r) * 4);
    const h2 f0 = u2h(pku(f.x, f.y)), f1 = u2h(pku(f.z, f.w));
    float x[8];
#pragma unroll
    for (int d = 0; d < 8; ++d)
        x[d] = fdot2(f0, u2h(wq[WOFF_FW + d*2]),
               fdot2(f1, u2h(wq[WOFF_FW + d*2 + 1]), bias[BOFF_FB + d]));

#pragma unroll
    for (int li = 0; li < 3; ++li) {
        const unsigned* W  = wq + WOFF_IPW + li * 96;   // 24 rows x 4 h2
        const float*    Bq = bias + BOFF_IPB + li * 24;

        h2 x2[4];
#pragma unroll
        for (int p = 0; p < 4; ++p) x2[p] = u2h(pku(x[2*p], x[2*p+1]));

        // k -> packed fp16 LDS (first: write->read gap hidden by v,q below)
        {
            float kv[8];
#pragma unroll
            for (int o = 0; o < 8; ++o) {
                const unsigned* w = W + (8 + o)*4;
                float a = Bq[8 + o];
#pragma unroll
                for (int p = 0; p < 4; ++p) a = fdot2(x2[p], u2h(w[p]), a);
                kv[o] = a;
            }
            uint4 K;
            K.x = pku(kv[0], kv[1]); K.y = pku(kv[2], kv[3]);
            K.z = pku(kv[4], kv[5]); K.w = pku(kv[6], kv[7]);
            kb[r][g] = K;
        }
        // v -> fp16 pair-transposed LDS (halfword scatter)
        {
#pragma unroll
            for (int o = 0; o < 8; ++o) {
                const unsigned* w = W + (16 + o)*4;
                float a = Bq[16 + o];
#pragma unroll
                for (int p = 0; p < 4; ++p) a = fdot2(x2[p], u2h(w[p]), a);
                vth[vwr + 2*o] = (_Float16)a;
            }
        }
        // q last (scale pre-folded into W/B)
        h2 q2[4];
#pragma unroll
        for (int h = 0; h < 4; ++h) {
            const unsigned* wa = W + (2*h)*4;
            const unsigned* wb = W + (2*h+1)*4;
            float qa = Bq[2*h], qb = Bq[2*h+1];
#pragma unroll
            for (int p = 0; p < 4; ++p) {
                qa = fdot2(x2[p], u2h(wa[p]), qa);
                qb = fdot2(x2[p], u2h(wb[p]), qb);
            }
            q2[h] = u2h(pku(qa, qb));
        }
        // Group's k/v LDS region is wave-private; DS ops in-order per wave.

        // --- attention over j-pairs, depth-1 software prefetch ---
        float o_[8] = {0.f,0.f,0.f,0.f,0.f,0.f,0.f,0.f};
        float sm[4] = {0.f,0.f,0.f,0.f};
        const h2 one2 = u2h(0x3C003C00u);

        uint4 cKa = kb[0][g];
        uint4 cKb = kb[1][g];
        uint4 cva = *reinterpret_cast<const uint4*>(&vt_dw[vrd]);
        uint4 cvb = *reinterpret_cast<const uint4*>(&vt_dw[vrd + 4]);
#pragma unroll
        for (int jp = 0; jp < 8; ++jp) {
            uint4 nKa, nKb, nva, nvb;
            if (jp < 7) {
                nKa = kb[2*jp + 2][g];
                nKb = kb[2*jp + 3][g];
                nva = *reinterpret_cast<const uint4*>(&vt_dw[vrd + (jp+1)*8]);
                nvb = *reinterpret_cast<const uint4*>(&vt_dw[vrd + (jp+1)*8 + 4]);
            }
            const float pa0 = __builtin_amdgcn_exp2f(fdot2(q2[0], u2h(cKa.x), 0.f));
            const float pa1 = __builtin_amdgcn_exp2f(fdot2(q2[1], u2h(cKa.y), 0.f));
            const float pa2 = __builtin_amdgcn_exp2f(fdot2(q2[2], u2h(cKa.z), 0.f));
            const float pa3 = __builtin_amdgcn_exp2f(fdot2(q2[3], u2h(cKa.w), 0.f));
            const float pb0 = __builtin_amdgcn_exp2f(fdot2(q2[0], u2h(cKb.x), 0.f));
            const float pb1 = __builtin_amdgcn_exp2f(fdot2(q2[1], u2h(cKb.y), 0.f));
            const float pb2 = __builtin_amdgcn_exp2f(fdot2(q2[2], u2h(cKb.z), 0.f));
            const float pb3 = __builtin_amdgcn_exp2f(fdot2(q2[3], u2h(cKb.w), 0.f));
            const h2 pp0 = u2h(pku(pa0, pb0));
            const h2 pp1 = u2h(pku(pa1, pb1));
            const h2 pp2 = u2h(pku(pa2, pb2));
            const h2 pp3 = u2h(pku(pa3, pb3));
            sm[0] = fdot2(pp0, one2, sm[0]);
            sm[1] = fdot2(pp1, one2, sm[1]);
            sm[2] = fdot2(pp2, one2, sm[2]);
            sm[3] = fdot2(pp3, one2, sm[3]);
            o_[0] = fdot2(pp0, u2h(cva.x), o_[0]);
            o_[1] = fdot2(pp0, u2h(cva.y), o_[1]);
            o_[2] = fdot2(pp1, u2h(cva.z), o_[2]);
            o_[3] = fdot2(pp1, u2h(cva.w), o_[3]);
            o_[4] = fdot2(pp2, u2h(cvb.x), o_[4]);
            o_[5] = fdot2(pp2, u2h(cvb.y), o_[5]);
            o_[6] = fdot2(pp3, u2h(cvb.z), o_[6]);
            o_[7] = fdot2(pp3, u2h(cvb.w), o_[7]);
            cKa = nKa; cKb = nKb; cva = nva; cvb = nvb;
        }

        // --- out-proj + residual + LN1 (1/sum folded into o2 pack) ---
        const unsigned* OW = wq + WOFF_OW + li * 32;
        const float*    OB = bias + BOFF_OB + li * 8;
        h2 o2[4];
#pragma unroll
        for (int h = 0; h < 4; ++h) {
            const float inv = __builtin_amdgcn_rcpf(sm[h]);
            o2[h] = u2h(pku(o_[2*h] * inv, o_[2*h+1] * inv));
        }
        float y[8];
#pragma unroll
        for (int d = 0; d < 8; ++d) {
            const unsigned* w = OW + d*4;
            float a = OB[d];
#pragma unroll
            for (int p = 0; p < 4; ++p) a = fdot2(o2[p], u2h(w[p]), a);
            y[d] = x[d] + a;
        }
        {
            const float* G  = bias + BOFF_N1G + li * 8;
            const float* Bb = bias + BOFF_N1B + li * 8;
            h2 y2[4];
#pragma unroll
            for (int p = 0; p < 4; ++p) y2[p] = u2h(pku(y[2*p], y[2*p+1]));
            float s1 = 0.f, s2 = 0.f;
#pragma unroll
            for (int p = 0; p < 4; ++p) {
                s1 = fdot2(y2[p], one2, s1);
                s2 = fdot2(y2[p], y2[p], s2);
            }
            const float m  = s1 * 0.125f;
            const float v  = fmaf(-m, m, s2 * 0.125f);
            const float rs = __builtin_amdgcn_rsqf(v + 1e-5f);
#pragma unroll
            for (int d = 0; d < 8; ++d) x[d] = G[d] * (y[d] - m) * rs + Bb[d];
        }

        // --- FFN (8->16->8, relu) + residual + LN2 ---
        const unsigned* W1  = wq + WOFF_L1W + li * 64;
        const float*    B1l = bias + BOFF_L1B + li * 16;
        const unsigned* W2  = wq + WOFF_L2W + li * 64;
        const float*    B2l = bias + BOFF_L2B + li * 8;
#pragma unroll
        for (int p = 0; p < 4; ++p) x2[p] = u2h(pku(x[2*p], x[2*p+1]));
        float hb[16];
#pragma unroll
        for (int o = 0; o < 16; ++o) {
            const unsigned* w = W1 + o*4;
            float a = B1l[o];
#pragma unroll
            for (int p = 0; p < 4; ++p) a = fdot2(x2[p], u2h(w[p]), a);
            hb[o] = a;
        }
        h2 hp[8];
#pragma unroll
        for (int p = 0; p < 8; ++p) hp[p] = relu2(u2h(pku(hb[2*p], hb[2*p+1])));
        float y8[8];
#pragma unroll
        for (int d = 0; d < 8; ++d) {
            const unsigned* w = W2 + d*8;
            float a = B2l[d];
#pragma unroll
            for (int p = 0; p < 8; ++p) a = fdot2(hp[p], u2h(w[p]), a);
            y8[d] = x[d] + a;
        }
        {
            const float* G  = bias + BOFF_N2G + li * 8;
            const float* Bb = bias + BOFF_N2B + li * 8;
            h2 y2[4];
#pragma unroll
            for (int p = 0; p < 4; ++p) y2[p] = u2h(pku(y8[2*p], y8[2*p+1]));
            float s1 = 0.f, s2 = 0.f;
#pragma unroll
            for (int p = 0; p < 4; ++p) {
                s1 = fdot2(y2[p], one2, s1);
                s2 = fdot2(y2[p], y2[p], s2);
            }
            const float m  = s1 * 0.125f;
            const float v  = fmaf(-m, m, s2 * 0.125f);
            const float rs = __builtin_amdgcn_rsqf(v + 1e-5f);
#pragma unroll
            for (int d = 0; d < 8; ++d) x[d] = G[d] * (y8[d] - m) * rs + Bb[d];
        }
    }

    // --- floors: sum over L (butterfly in 16-lane segment) -> LDS (fp32) ---
#pragma unroll
    for (int d = 0; d < 8; ++d) {
        float t = x[d];
        t += __shfl_xor(t, 1, 16);
        t += __shfl_xor(t, 2, 16);
        t += __shfl_xor(t, 4, 16);
        t += __shfl_xor(t, 8, 16);
        x[d] = t;
    }
    if (r == 0) {
#pragma unroll
        for (int d = 0; d < 8; ++d) floors_lds[g][d] = x[d];
    }
    __syncthreads();

    // --- tail phase 1: units[bl][ou] = sum_fl relu(floors . uw[ou] + ub[ou]) ---
    {
        const int bl = tid >> 7;          // local batch (0..1)
        const int ou = (tid >> 3) & 15;   // unit output (0..15)
        const int fl = tid & 7;           // floor index (0..7)
        float acc = ub[ou];
        const float* fp = &floors_lds[bl*8 + fl][0];
#pragma unroll
        for (int d = 0; d < 8; ++d) acc += fp[d] * uw[ou*8 + d];
        acc = fmaxf(acc, 0.f);
        acc += __shfl_xor(acc, 1, 8);
        acc += __shfl_xor(acc, 2, 8);
        acc += __shfl_xor(acc, 4, 8);
        if (fl == 0) units_lds[bl][ou] = acc;
    }
    __syncthreads();

    // --- tail phase 2: match MLP partials (40 threads: 2 batches x 20 hidden) ---
    if (tid < 40) {
        const int bl = tid / 20, o = tid % 20;
        const int bg = blockIdx.x * 2 + bl;       // global batch
        const float* w1o = w1 + o*42;
        float base = b1[o];
        const int ci = cidxs[bg], si = slots[bg];
#pragma unroll
        for (int j = 0; j < 8; ++j)  base += tab_c[ci*8 + j]  * w1o[j];
#pragma unroll
        for (int j = 0; j < 8; ++j)  base += tab_s[si*8 + j]  * w1o[8 + j];
#pragma unroll
        for (int j = 0; j < 16; ++j) base += units_lds[bl][j] * w1o[16 + j];
#pragma unroll
        for (int j = 0; j < 4; ++j)  base += f2[bg*4 + j]     * w1o[32 + j];
        const float w2o = w2[o];
#pragma unroll
        for (int k = 0; k < 4; ++k) {
            float t = base;
#pragma unroll
            for (int j = 0; j < 6; ++j)
                t += f3[((size_t)bg*4 + k)*6 + j] * w1o[36 + j];
            pm_lds[bl][k][o] = fmaxf(t, 0.f) * w2o;
        }
    }
    __syncthreads();

    // --- tail phase 3: reduce + write outputs ---
    if (tid < 8) {
        const int bl = tid >> 2, k = tid & 3;
        float acc = b2[0];
#pragma unroll
        for (int o = 0; o < 20; ++o) acc += pm_lds[bl][k][o];
        out[(size_t)(blockIdx.x*2 + bl)*4 + k] = acc;
    }
    if (tid < 2)
        out[(size_t)B_*K_ + blockIdx.x*2 + tid] = 4.0f;   // nf3 = K
}

extern "C" void kernel_launch(void* const* d_in, const int* in_sizes, int n_in,
                              void* d_out, int out_size, void* d_ws, size_t ws_size,
                              hipStream_t stream)
{
    const int*   cidxs  = (const int*)  d_in[0];
    const int*   slots  = (const int*)  d_in[1];
    const float* gfeats = (const float*)d_in[2];
    const float* f2     = (const float*)d_in[3];
    const float* f3     = (const float*)d_in[4];
    const float* tab_c  = (const float*)d_in[5];
    const float* tab_s  = (const float*)d_in[6];
    const float* fw     = (const float*)d_in[7];
    const float* fb     = (const float*)d_in[8];
    const float* ipw    = (const float*)d_in[9];
    const float* ipb    = (const float*)d_in[10];
    const float* ow     = (const float*)d_in[11];
    const float* ob     = (const float*)d_in[12];
    const float* l1w    = (const float*)d_in[13];
    const float* l1b    = (const float*)d_in[14];
    const float* l2w    = (const float*)d_in[15];
    const float* l2b    = (const float*)d_in[16];
    const float* n1g    = (const float*)d_in[17];
    const float* n1b    = (const float*)d_in[18];
    const float* n2g    = (const float*)d_in[19];
    const float* n2b    = (const float*)d_in[20];
    const float* uw     = (const float*)d_in[21];
    const float* ub     = (const float*)d_in[22];
    const float* w1     = (const float*)d_in[23];
    const float* b1     = (const float*)d_in[24];
    const float* w2     = (const float*)d_in[25];
    const float* b2     = (const float*)d_in[26];

    fused_kernel<<<SEQS_ / 16, 256, 0, stream>>>(
        gfeats, fw, ipw, ow, l1w, l2w,
        fb, ipb, ob, l1b, l2b, n1g, n1b, n2g, n2b,
        cidxs, slots, f2, f3, tab_c, tab_s, uw, ub, w1, b1, w2, b2,
        (float*)d_out);
}